// Round 1
// baseline (1978.515 us; speedup 1.0000x reference)
//
#include <hip/hip_runtime.h>

typedef unsigned short u16;
typedef __bf16 bf16x8 __attribute__((ext_vector_type(8)));
typedef float f32x4 __attribute__((ext_vector_type(4)));
typedef unsigned int u32;

#define EPSF 1e-6f

__device__ __forceinline__ u16 f2bf(float f) {
  union { float f; unsigned u; } un; un.f = f;
  unsigned r = un.u + 0x7FFFu + ((un.u >> 16) & 1u);
  return (u16)(r >> 16);
}

__device__ __forceinline__ float block_sum(float v) {
  #pragma unroll
  for (int off = 32; off > 0; off >>= 1) v += __shfl_xor(v, off, 64);
  __shared__ float ws[4];
  const int w = threadIdx.x >> 6;
  __syncthreads();
  if ((threadIdx.x & 63) == 0) ws[w] = v;
  __syncthreads();
  return ws[0] + ws[1] + ws[2] + ws[3];
}

// async global->LDS, 16B per lane. LDS dest must be wave-uniform base; HW adds lane*16.
__device__ __forceinline__ void lds_cp16(const void* g, void* l) {
  __builtin_amdgcn_global_load_lds(
      (__attribute__((address_space(1))) void*)g,
      (__attribute__((address_space(3))) void*)l, 16, 0, 0);
}

// ---------------- embedding: x[b*T+t][d] = tok[idx][d] + pos[t][d] ----------------
__global__ __launch_bounds__(256) void embed_kernel(
    const int* __restrict__ idx, const float* __restrict__ tok,
    const float* __restrict__ pos, float* __restrict__ x) {
  const int row = blockIdx.x;           // b*T + t
  const int tpos = row & 1023;
  const int token = idx[row];
  const int d = threadIdx.x * 4;
  const float4 a = *(const float4*)(tok + (long)token * 1024 + d);
  const float4 b = *(const float4*)(pos + (long)tpos * 1024 + d);
  float4 o; o.x = a.x + b.x; o.y = a.y + b.y; o.z = a.z + b.z; o.w = a.w + b.w;
  *(float4*)(x + (long)row * 1024 + d) = o;
}

// ---------------- anorm: h = bf16( gain * x / (mean|x| + eps) ) ----------------
__global__ __launch_bounds__(256) void anorm_kernel(
    const float* __restrict__ x, const float* __restrict__ gain,
    u16* __restrict__ h) {
  const int row = blockIdx.x;
  const int tid = threadIdx.x;
  const float4 v = *(const float4*)(x + (long)row * 1024 + tid * 4);
  float s = fabsf(v.x) + fabsf(v.y) + fabsf(v.z) + fabsf(v.w);
  s = block_sum(s);
  const float scale = 1.0f / (s * (1.0f / 1024.0f) + EPSF);
  const float4 g = *(const float4*)(gain + tid * 4);
  ushort4 o;
  o.x = f2bf(v.x * g.x * scale);
  o.y = f2bf(v.y * g.y * scale);
  o.z = f2bf(v.z * g.z * scale);
  o.w = f2bf(v.w * g.w * scale);
  *(ushort4*)(h + (long)row * 1024 + tid * 4) = o;
}

// ------- rational softmax rows: stats pre-mask, mask=-1000 post-scale, p^4 norm -------
__global__ __launch_bounds__(256) void rsm_kernel(
    const float* __restrict__ scores, u16* __restrict__ attn,
    const float* __restrict__ score_gain, int l) {
  const int bid = blockIdx.x;           // h*1024 + q
  const int qpos = bid & 1023;
  const float* rowp = scores + (long)bid * 1024;
  const int tid = threadIdx.x;
  const float4 v = *(const float4*)(rowp + tid * 4);
  const float ssum = block_sum(v.x + v.y + v.z + v.w);
  const float mean = ssum * (1.0f / 1024.0f);
  float dv[4] = { v.x - mean, v.y - mean, v.z - mean, v.w - mean };
  const float asum = block_sum(fabsf(dv[0]) + fabsf(dv[1]) + fabsf(dv[2]) + fabsf(dv[3]));
  const float mad = asum * (1.0f / 1024.0f) + EPSF;
  const float gscale = score_gain[l] / mad;
  float p[4];
  float psum = 0.0f;
  const int base = tid * 4;
  #pragma unroll
  for (int u = 0; u < 4; u++) {
    float sv = dv[u] * gscale;
    if (base + u > qpos) sv = -1000.0f;
    const float r = sv / (fabsf(sv) + 1.0f);
    const float q1 = (r + 1.0f) * 0.5f;
    const float q2 = q1 * q1;
    p[u] = q2 * q2;
    psum += p[u];
  }
  psum = block_sum(psum);
  const float inv = 1.0f / (psum + EPSF);
  ushort4 o;
  o.x = f2bf(p[0] * inv); o.y = f2bf(p[1] * inv);
  o.z = f2bf(p[2] * inv); o.w = f2bf(p[3] * inv);
  *(ushort4*)(attn + (long)bid * 1024 + tid * 4) = o;
}

// ---------------- weight convert: dst[c][r] = bf16(src[r][c]), src f32 [R][C] ----------------
__global__ __launch_bounds__(256) void wconv_kernel(
    const float* __restrict__ src, u16* __restrict__ dst, int R, int C) {
  __shared__ float tile[32][33];
  const int c0 = blockIdx.x * 32, r0 = blockIdx.y * 32;
  const int tx = threadIdx.x, ty = threadIdx.y;
  #pragma unroll
  for (int i = 0; i < 4; i++)
    tile[ty + 8 * i][tx] = src[(long)(r0 + ty + 8 * i) * C + c0 + tx];
  __syncthreads();
  #pragma unroll
  for (int i = 0; i < 4; i++)
    dst[(long)(c0 + ty + 8 * i) * R + r0 + tx] = f2bf(tile[tx][ty + 8 * i]);
}

// ---------------- v_t[b,h,dh,t] = qkv[b*T+t][2048 + h*64 + dh] (bf16 transpose) ----------------
__global__ __launch_bounds__(256) void build_vt(
    const u16* __restrict__ qkv, u16* __restrict__ v_t) {
  __shared__ u16 tile[32][33];
  const int z = blockIdx.z, b = z >> 4, h = z & 15;
  const u16* src = qkv + (long)b * 1024 * 3072 + 2048 + h * 64;  // [t][dh], lda 3072
  u16* dst = v_t + (long)z * 64 * 1024;                          // [dh][t], ldd 1024
  const int t0 = blockIdx.x * 32, d0 = blockIdx.y * 32;
  const int tx = threadIdx.x, ty = threadIdx.y;
  #pragma unroll
  for (int i = 0; i < 4; i++)
    tile[ty + 8 * i][tx] = src[(long)(t0 + ty + 8 * i) * 3072 + d0 + tx];
  __syncthreads();
  #pragma unroll
  for (int i = 0; i < 4; i++)
    dst[(long)(d0 + ty + 8 * i) * 1024 + t0 + tx] = tile[tx][ty + 8 * i];
}

// ---------------- bqkv[l*3072 + j] = concat(bq[l], bk[l], bv[l]) ----------------
__global__ __launch_bounds__(256) void bias_concat(
    const float* __restrict__ bq, const float* __restrict__ bk,
    const float* __restrict__ bv, float* __restrict__ out) {
  const int i = blockIdx.x * 256 + threadIdx.x;   // < L*3072
  const int l = i / 3072, j = i % 3072;
  float v;
  if (j < 1024)      v = bq[l * 1024 + j];
  else if (j < 2048) v = bk[l * 1024 + j - 1024];
  else               v = bv[l * 1024 + j - 2048];
  out[i] = v;
}

// ---------------- generic bf16 MFMA GEMM: C = A[M,K] @ Bt[N,K]^T ----------------
// 128x128 tile, BK=32, 4 waves (2x2 of 64x64), mfma_f32_16x16x32_bf16.
template <bool OUT_BF16, bool BIAS, bool RELU, bool RESID>
__global__ __launch_bounds__(256) void gemm_kernel(
    const u16* __restrict__ A, long lda, long sA,
    const u16* __restrict__ Bt, long ldb, long sB,
    void* __restrict__ Cv, long ldc, long sC,
    const float* __restrict__ bias, const float* __restrict__ resid,
    int M, int N, int K, int ntn) {
  __shared__ u16 lA[128 * 32];
  __shared__ u16 lB[128 * 32];
  const int tm = blockIdx.x / ntn, tn = blockIdx.x % ntn;
  const int batch = blockIdx.y;
  const int t = threadIdx.x, w = t >> 6, l = t & 63;
  A  += (long)batch * sA;
  Bt += (long)batch * sB;
  const int rowA0 = tm * 128, rowB0 = tn * 128;
  const int srow = (w << 4) + (l >> 2);   // staging row 0..63 (call adds +64)
  const int skel = (l & 3) << 3;          // staging k element 0,8,16,24
  const int wr = (w >> 1) << 6, wc = (w & 1) << 6;
  const int lrow = l & 15, kgrp = l >> 4;
  f32x4 acc[4][4] = {};

  for (int k0 = 0; k0 < K; k0 += 32) {
    int rB1 = rowB0 + srow;      if (rB1 >= N) rB1 = N - 1;
    int rB2 = rowB0 + 64 + srow; if (rB2 >= N) rB2 = N - 1;
    lds_cp16(A  + (long)(rowA0 + srow) * lda + k0 + skel,      &lA[w * 512]);
    lds_cp16(A  + (long)(rowA0 + 64 + srow) * lda + k0 + skel, &lA[2048 + w * 512]);
    lds_cp16(Bt + (long)rB1 * ldb + k0 + skel,                 &lB[w * 512]);
    lds_cp16(Bt + (long)rB2 * ldb + k0 + skel,                 &lB[2048 + w * 512]);
    __syncthreads();
    bf16x8 af[4], bfr[4];
    #pragma unroll
    for (int m = 0; m < 4; m++)
      af[m] = *(const bf16x8*)&lA[(wr + m * 16 + lrow) * 32 + kgrp * 8];
    #pragma unroll
    for (int n = 0; n < 4; n++)
      bfr[n] = *(const bf16x8*)&lB[(wc + n * 16 + lrow) * 32 + kgrp * 8];
    #pragma unroll
    for (int m = 0; m < 4; m++)
      #pragma unroll
      for (int n = 0; n < 4; n++)
        acc[m][n] = __builtin_amdgcn_mfma_f32_16x16x32_bf16(af[m], bfr[n], acc[m][n], 0, 0, 0);
    __syncthreads();
  }

  #pragma unroll
  for (int m = 0; m < 4; m++) {
    #pragma unroll
    for (int n = 0; n < 4; n++) {
      const int col = rowB0 + wc + n * 16 + lrow;
      #pragma unroll
      for (int j = 0; j < 4; j++) {
        const int row = rowA0 + wr + m * 16 + kgrp * 4 + j;
        if (row < M && col < N) {
          float v = acc[m][n][j];
          if (BIAS) v += bias[col];
          if (RELU) v = fmaxf(v, 0.0f);
          const long off = (long)batch * sC + (long)row * ldc + col;
          if (RESID) v += resid[off];
          if (OUT_BF16) ((u16*)Cv)[off] = f2bf(v);
          else          ((float*)Cv)[off] = v;
        }
      }
    }
  }
}

extern "C" void kernel_launch(void* const* d_in, const int* in_sizes, int n_in,
                              void* d_out, int out_size, void* d_ws, size_t ws_size,
                              hipStream_t stream) {
  constexpr int Lc = 4, Tc = 1024, Dc = 1024, Hc = 16, Fc = 4096, DHc = 64;
  const int M = 2 * Tc;  // 2048 rows

  const int*   idxp       = (const int*)  d_in[0];
  const float* tok_emb    = (const float*)d_in[1];
  const float* pos_emb    = (const float*)d_in[2];
  const float* Wq         = (const float*)d_in[3];
  const float* bq         = (const float*)d_in[4];
  const float* Wk         = (const float*)d_in[5];
  const float* bk         = (const float*)d_in[6];
  const float* Wv         = (const float*)d_in[7];
  const float* bv         = (const float*)d_in[8];
  const float* Wo         = (const float*)d_in[9];
  const float* bo         = (const float*)d_in[10];
  const float* score_gain = (const float*)d_in[11];
  const float* norm1_gain = (const float*)d_in[12];
  const float* norm2_gain = (const float*)d_in[13];
  const float* W1         = (const float*)d_in[14];
  const float* b1         = (const float*)d_in[15];
  const float* W2         = (const float*)d_in[16];
  const float* b2         = (const float*)d_in[17];
  const float* final_gain = (const float*)d_in[18];
  const float* Wlm        = (const float*)d_in[19];
  const float* blm        = (const float*)d_in[20];

  char* p = (char*)d_ws;
  auto alloc = [&](size_t n) { char* r = p; p += (n + 255) & ~(size_t)255; return r; };
  u16*  wqkv_t = (u16*) alloc((size_t)Lc * 3072 * 1024 * 2);
  u16*  wo_t   = (u16*) alloc((size_t)Lc * 1024 * 1024 * 2);
  u16*  w1_t   = (u16*) alloc((size_t)Lc * 4096 * 1024 * 2);
  u16*  w2_t   = (u16*) alloc((size_t)Lc * 1024 * 4096 * 2);
  u16*  wlm_t  = (u16*) alloc((size_t)32000 * 1024 * 2);
  float* bqkv  = (float*)alloc((size_t)Lc * 3072 * 4);
  float* x     = (float*)alloc((size_t)M * 1024 * 4);
  u16*  hbuf   = (u16*) alloc((size_t)M * 1024 * 2);
  u16*  qkv    = (u16*) alloc((size_t)M * 3072 * 2);
  u16*  v_t    = (u16*) alloc((size_t)2 * Hc * DHc * Tc * 2);
  u16*  obuf   = (u16*) alloc((size_t)M * 1024 * 2);
  u16*  ffh    = (u16*) alloc((size_t)M * 4096 * 2);
  float* scores= (float*)alloc((size_t)Hc * Tc * Tc * 4);   // one batch elem at a time
  u16*  attn   = (u16*) alloc((size_t)Hc * Tc * Tc * 2);

  const dim3 tb(32, 8);
  // ---- weight conversion (f32 -> bf16 transposed) ----
  for (int l = 0; l < Lc; l++) {
    wconv_kernel<<<dim3(32, 32), tb, 0, stream>>>(Wq + (size_t)l * Dc * Dc, wqkv_t + ((size_t)l * 3072 + 0) * 1024, 1024, 1024);
    wconv_kernel<<<dim3(32, 32), tb, 0, stream>>>(Wk + (size_t)l * Dc * Dc, wqkv_t + ((size_t)l * 3072 + 1024) * 1024, 1024, 1024);
    wconv_kernel<<<dim3(32, 32), tb, 0, stream>>>(Wv + (size_t)l * Dc * Dc, wqkv_t + ((size_t)l * 3072 + 2048) * 1024, 1024, 1024);
    wconv_kernel<<<dim3(32, 32), tb, 0, stream>>>(Wo + (size_t)l * Dc * Dc, wo_t + (size_t)l * 1024 * 1024, 1024, 1024);
    wconv_kernel<<<dim3(128, 32), tb, 0, stream>>>(W1 + (size_t)l * Dc * Fc, w1_t + (size_t)l * Fc * Dc, 1024, 4096);
    wconv_kernel<<<dim3(32, 128), tb, 0, stream>>>(W2 + (size_t)l * Fc * Dc, w2_t + (size_t)l * Dc * Fc, 4096, 1024);
  }
  wconv_kernel<<<dim3(1000, 32), tb, 0, stream>>>(Wlm, wlm_t, 1024, 32000);
  bias_concat<<<48, 256, 0, stream>>>(bq, bk, bv, bqkv);

  embed_kernel<<<M, 256, 0, stream>>>(idxp, tok_emb, pos_emb, x);

  for (int l = 0; l < Lc; l++) {
    // x -> h (anorm1), then fused QKV gemm -> qkv bf16 [M][3072]
    anorm_kernel<<<M, 256, 0, stream>>>(x, norm1_gain + (size_t)l * Dc, hbuf);
    gemm_kernel<true, true, false, false><<<dim3(16 * 24, 1), 256, 0, stream>>>(
        hbuf, 1024, 0, wqkv_t + (size_t)l * 3072 * 1024, 1024, 0,
        qkv, 3072, 0, bqkv + (size_t)l * 3072, nullptr, M, 3072, 1024, 24);
    build_vt<<<dim3(32, 2, 32), tb, 0, stream>>>(qkv, v_t);

    for (int b = 0; b < 2; b++) {
      const u16* qb = qkv + (size_t)b * Tc * 3072;
      // scores[h][q][k'] = q . k   (batched over h)
      gemm_kernel<false, false, false, false><<<dim3(64, 16), 256, 0, stream>>>(
          qb, 3072, 64, qb + 1024, 3072, 64,
          scores, 1024, (long)Tc * Tc, nullptr, nullptr, 1024, 1024, 64, 8);
      rsm_kernel<<<Hc * Tc, 256, 0, stream>>>(scores, attn, score_gain, l);
      // o[t][dh] = attn @ v  -> strided view into obuf [M][1024]
      gemm_kernel<true, false, false, false><<<dim3(8, 16), 256, 0, stream>>>(
          attn, 1024, (long)Tc * Tc, v_t + (size_t)b * Hc * DHc * Tc, 1024, (long)DHc * Tc,
          obuf + (size_t)b * Tc * Dc, 1024, DHc, nullptr, nullptr, 1024, 64, 1024, 1);
    }
    // x += o @ Wo + bo
    gemm_kernel<false, true, false, true><<<dim3(16 * 8, 1), 256, 0, stream>>>(
        obuf, 1024, 0, wo_t + (size_t)l * 1024 * 1024, 1024, 0,
        x, 1024, 0, bo + (size_t)l * 1024, x, M, 1024, 1024, 8);
    // FFN
    anorm_kernel<<<M, 256, 0, stream>>>(x, norm2_gain + (size_t)l * Dc, hbuf);
    gemm_kernel<true, true, true, false><<<dim3(16 * 32, 1), 256, 0, stream>>>(
        hbuf, 1024, 0, w1_t + (size_t)l * Fc * Dc, 1024, 0,
        ffh, 4096, 0, b1 + (size_t)l * Fc, nullptr, M, 4096, 1024, 32);
    gemm_kernel<false, true, false, true><<<dim3(16 * 8, 1), 256, 0, stream>>>(
        ffh, 4096, 0, w2_t + (size_t)l * Dc * Fc, 4096, 0,
        x, 1024, 0, b2 + (size_t)l * Dc, x, M, 1024, 4096, 8);
  }

  // final norm + LM head -> d_out f32 [2048][32000]
  anorm_kernel<<<M, 256, 0, stream>>>(x, final_gain, hbuf);
  gemm_kernel<false, true, false, false><<<dim3(16 * 250, 1), 256, 0, stream>>>(
      hbuf, 1024, 0, wlm_t, 1024, 0,
      d_out, 32000, 0, blm, nullptr, M, 32000, 1024, 250);
}

// Round 2
// 1929.683 us; speedup vs baseline: 1.0253x; 1.0253x over previous
//
#include <hip/hip_runtime.h>

typedef unsigned short u16;
typedef __bf16 bf16x8 __attribute__((ext_vector_type(8)));
typedef float f32x4 __attribute__((ext_vector_type(4)));
typedef unsigned int u32;

#define EPSF 1e-6f

__device__ __forceinline__ u16 f2bf(float f) {
  union { float f; unsigned u; } un; un.f = f;
  unsigned r = un.u + 0x7FFFu + ((un.u >> 16) & 1u);
  return (u16)(r >> 16);
}

__device__ __forceinline__ float block_sum(float v) {
  #pragma unroll
  for (int off = 32; off > 0; off >>= 1) v += __shfl_xor(v, off, 64);
  __shared__ float ws[4];
  const int w = threadIdx.x >> 6;
  __syncthreads();
  if ((threadIdx.x & 63) == 0) ws[w] = v;
  __syncthreads();
  return ws[0] + ws[1] + ws[2] + ws[3];
}

// async global->LDS, 16B per lane. LDS dest must be wave-uniform base; HW adds lane*16.
__device__ __forceinline__ void lds_cp16(const void* g, void* l) {
  __builtin_amdgcn_global_load_lds(
      (__attribute__((address_space(1))) void*)g,
      (__attribute__((address_space(3))) void*)l, 16, 0, 0);
}

// ---------------- embedding ----------------
__global__ __launch_bounds__(256) void embed_kernel(
    const int* __restrict__ idx, const float* __restrict__ tok,
    const float* __restrict__ pos, float* __restrict__ x) {
  const int row = blockIdx.x;
  const int tpos = row & 1023;
  const int token = idx[row];
  const int d = threadIdx.x * 4;
  const float4 a = *(const float4*)(tok + (long)token * 1024 + d);
  const float4 b = *(const float4*)(pos + (long)tpos * 1024 + d);
  float4 o; o.x = a.x + b.x; o.y = a.y + b.y; o.z = a.z + b.z; o.w = a.w + b.w;
  *(float4*)(x + (long)row * 1024 + d) = o;
}

// ---------------- anorm ----------------
__global__ __launch_bounds__(256) void anorm_kernel(
    const float* __restrict__ x, const float* __restrict__ gain,
    u16* __restrict__ h) {
  const int row = blockIdx.x;
  const int tid = threadIdx.x;
  const float4 v = *(const float4*)(x + (long)row * 1024 + tid * 4);
  float s = fabsf(v.x) + fabsf(v.y) + fabsf(v.z) + fabsf(v.w);
  s = block_sum(s);
  const float scale = 1.0f / (s * (1.0f / 1024.0f) + EPSF);
  const float4 g = *(const float4*)(gain + tid * 4);
  ushort4 o;
  o.x = f2bf(v.x * g.x * scale);
  o.y = f2bf(v.y * g.y * scale);
  o.z = f2bf(v.z * g.z * scale);
  o.w = f2bf(v.w * g.w * scale);
  *(ushort4*)(h + (long)row * 1024 + tid * 4) = o;
}

// ---- fused scores + rational softmax: one block = 32 q-rows x 1024 cols, one (b,h) ----
// grid: (32 q-tiles, 16 heads, 2 batch). 256 threads, 4 waves.
__global__ __launch_bounds__(256) void score_kernel(
    const u16* __restrict__ qkv,      // [b][t][3072] bf16
    u16* __restrict__ attn,           // [(b*16+h)][1024][1024] bf16
    const float* __restrict__ score_gain, int l) {
  __shared__ float S[32][1024];       // 128 KiB score panel
  __shared__ u16 kbuf[128 * 64];      // 16 KiB K tile (slot-swizzled)
  __shared__ u16 qbuf[32 * 64];       // 4 KiB Q tile (slot-swizzled)
  const int qt = blockIdx.x, h = blockIdx.y, b = blockIdx.z;
  const int t = threadIdx.x, w = t >> 6, l64 = t & 63;
  const int q0 = qt * 32;
  const u16* Qg = qkv + (size_t)b * 1024 * 3072 + h * 64;
  const u16* Kg = Qg + 1024;

  // stage qbuf: chunk t -> LDS (row=t>>3, slot=t&7); source slot = slot ^ (row&7)
  {
    const int row = t >> 3, slot = t & 7;
    const int gslot = slot ^ (row & 7);
    lds_cp16(Qg + (size_t)(q0 + row) * 3072 + gslot * 8, &qbuf[w * 512]);
  }

  const int lrow = l64 & 15, kgrp = l64 >> 4;
  const int qstripe = (w & 1) * 16, chalf = (w >> 1) * 64;
  const int aswz = lrow & 7;

  for (int ct = 0; ct < 8; ct++) {
    __syncthreads();   // prev iter's kbuf reads done (iter0: drains qbuf load too)
    #pragma unroll
    for (int i = 0; i < 4; i++) {
      const int c = i * 256 + t;
      const int row = c >> 3, slot = c & 7;
      const int gslot = slot ^ (row & 7);
      lds_cp16(Kg + (size_t)(ct * 128 + row) * 3072 + gslot * 8,
               &kbuf[(i * 256 + w * 64) * 8]);
    }
    __syncthreads();
    bf16x8 af[2];
    #pragma unroll
    for (int kk = 0; kk < 2; kk++)
      af[kk] = *(const bf16x8*)&qbuf[(qstripe + lrow) * 64 + (((kk << 2) + kgrp) ^ aswz) * 8];
    #pragma unroll
    for (int n = 0; n < 4; n++) {
      f32x4 acc = {0.f, 0.f, 0.f, 0.f};
      #pragma unroll
      for (int kk = 0; kk < 2; kk++) {
        const bf16x8 bf = *(const bf16x8*)&kbuf[(chalf + n * 16 + lrow) * 64 +
                                                (((kk << 2) + kgrp) ^ aswz) * 8];
        acc = __builtin_amdgcn_mfma_f32_16x16x32_bf16(af[kk], bf, acc, 0, 0, 0);
      }
      const int col = ct * 128 + chalf + n * 16 + lrow;   // C col = lane&15
      #pragma unroll
      for (int j = 0; j < 4; j++)
        S[qstripe + kgrp * 4 + j][col] = acc[j];          // C row = (lane>>4)*4+j
    }
  }
  __syncthreads();

  // ---- per-row stats + rational softmax (8 rows per wave, whole wave per row) ----
  const float gain = score_gain[l];
  u16* arow_base = attn + ((size_t)(b * 16 + h) * 1024 + q0) * 1024;
  #pragma unroll 1
  for (int r = 0; r < 8; r++) {
    const int row = w * 8 + r;
    const int qglob = q0 + row;
    float s = 0.f;
    #pragma unroll
    for (int i = 0; i < 8; i++) {
      const float2 v = *(const float2*)&S[row][l64 * 2 + i * 128];
      s += v.x + v.y;
    }
    #pragma unroll
    for (int off = 32; off; off >>= 1) s += __shfl_xor(s, off, 64);
    const float mean = s * (1.0f / 1024.0f);
    float a = 0.f;
    #pragma unroll
    for (int i = 0; i < 8; i++) {
      const float2 v = *(const float2*)&S[row][l64 * 2 + i * 128];
      a += fabsf(v.x - mean) + fabsf(v.y - mean);
    }
    #pragma unroll
    for (int off = 32; off; off >>= 1) a += __shfl_xor(a, off, 64);
    const float gs = gain / (a * (1.0f / 1024.0f) + EPSF);
    float ps = 0.f;
    #pragma unroll
    for (int i = 0; i < 8; i++) {
      const int cp = l64 * 2 + i * 128;
      float2 v = *(const float2*)&S[row][cp];
      float sv0 = (v.x - mean) * gs;
      float sv1 = (v.y - mean) * gs;
      if (cp > qglob)     sv0 = -1000.0f;
      if (cp + 1 > qglob) sv1 = -1000.0f;
      const float r0 = sv0 / (fabsf(sv0) + 1.0f);
      const float r1 = sv1 / (fabsf(sv1) + 1.0f);
      const float a0 = (r0 + 1.0f) * 0.5f, a1 = (r1 + 1.0f) * 0.5f;
      const float b0 = a0 * a0, b1 = a1 * a1;
      float2 pv; pv.x = b0 * b0; pv.y = b1 * b1;
      *(float2*)&S[row][cp] = pv;
      ps += pv.x + pv.y;
    }
    #pragma unroll
    for (int off = 32; off; off >>= 1) ps += __shfl_xor(ps, off, 64);
    const float inv = 1.0f / (ps + EPSF);
    u16* arow = arow_base + (size_t)row * 1024;
    #pragma unroll
    for (int i = 0; i < 8; i++) {
      const int cp = l64 * 2 + i * 128;
      const float2 v = *(const float2*)&S[row][cp];
      const u32 packed = (u32)f2bf(v.x * inv) | ((u32)f2bf(v.y * inv) << 16);
      *(u32*)&arow[cp] = packed;
    }
  }
}

// ---------------- weight convert: dst[c][r] = bf16(src[r][c]) ----------------
__global__ __launch_bounds__(256) void wconv_kernel(
    const float* __restrict__ src, u16* __restrict__ dst, int R, int C) {
  __shared__ float tile[32][33];
  const int c0 = blockIdx.x * 32, r0 = blockIdx.y * 32;
  const int tx = threadIdx.x, ty = threadIdx.y;
  #pragma unroll
  for (int i = 0; i < 4; i++)
    tile[ty + 8 * i][tx] = src[(long)(r0 + ty + 8 * i) * C + c0 + tx];
  __syncthreads();
  #pragma unroll
  for (int i = 0; i < 4; i++)
    dst[(long)(c0 + ty + 8 * i) * R + r0 + tx] = f2bf(tile[tx][ty + 8 * i]);
}

// ---------------- v_t[(b*16+h)][dh][t] = qkv[b*T+t][2048 + h*64 + dh] ----------------
__global__ __launch_bounds__(256) void build_vt(
    const u16* __restrict__ qkv, u16* __restrict__ v_t) {
  __shared__ u16 tile[32][33];
  const int z = blockIdx.z, b = z >> 4, h = z & 15;
  const u16* src = qkv + (long)b * 1024 * 3072 + 2048 + h * 64;
  u16* dst = v_t + (long)z * 64 * 1024;
  const int t0 = blockIdx.x * 32, d0 = blockIdx.y * 32;
  const int tx = threadIdx.x, ty = threadIdx.y;
  #pragma unroll
  for (int i = 0; i < 4; i++)
    tile[ty + 8 * i][tx] = src[(long)(t0 + ty + 8 * i) * 3072 + d0 + tx];
  __syncthreads();
  #pragma unroll
  for (int i = 0; i < 4; i++)
    dst[(long)(d0 + ty + 8 * i) * 1024 + t0 + tx] = tile[tx][ty + 8 * i];
}

__global__ __launch_bounds__(256) void bias_concat(
    const float* __restrict__ bq, const float* __restrict__ bk,
    const float* __restrict__ bv, float* __restrict__ out) {
  const int i = blockIdx.x * 256 + threadIdx.x;
  const int l = i / 3072, j = i % 3072;
  float v;
  if (j < 1024)      v = bq[l * 1024 + j];
  else if (j < 2048) v = bk[l * 1024 + j - 1024];
  else               v = bv[l * 1024 + j - 2048];
  out[i] = v;
}

// ---------------- generic bf16 MFMA GEMM: C = A[M,K] @ Bt[N,K]^T ----------------
// 128x128 tile, BK=32, 4 waves. tm-fast block order (B-panel reuse) + bijective XCD swizzle.
template <bool OUT_BF16, bool BIAS, bool RELU, bool RESID>
__global__ __launch_bounds__(256) void gemm_kernel(
    const u16* __restrict__ A, long lda, long sA,
    const u16* __restrict__ Bt, long ldb, long sB,
    void* __restrict__ Cv, long ldc, long sC, int cdiv, long sC2,
    const float* __restrict__ bias, const float* __restrict__ resid,
    int M, int N, int K, int nTM) {
  __shared__ u16 lA[128 * 32];
  __shared__ u16 lB[128 * 32];
  // bijective XCD swizzle (m204), then tm-fast decode
  const int nwg = gridDim.x;
  const int qx = nwg >> 3, rx = nwg & 7;
  const int xcd = blockIdx.x & 7, seq = blockIdx.x >> 3;
  const int wg = (xcd < rx ? xcd * (qx + 1) : rx * (qx + 1) + (xcd - rx) * qx) + seq;
  const int tm = wg % nTM, tn = wg / nTM;
  const int batch = blockIdx.y;
  const int t = threadIdx.x, w = t >> 6, l = t & 63;
  A  += (long)batch * sA;
  Bt += (long)batch * sB;
  const int rowA0 = tm * 128, rowB0 = tn * 128;
  const int srow = (w << 4) + (l >> 2);
  const int skel = (l & 3) << 3;
  const int wr = (w >> 1) << 6, wc = (w & 1) << 6;
  const int lrow = l & 15, kgrp = l >> 4;
  f32x4 acc[4][4] = {};

  for (int k0 = 0; k0 < K; k0 += 32) {
    int rB1 = rowB0 + srow;      if (rB1 >= N) rB1 = N - 1;
    int rB2 = rowB0 + 64 + srow; if (rB2 >= N) rB2 = N - 1;
    lds_cp16(A  + (long)(rowA0 + srow) * lda + k0 + skel,      &lA[w * 512]);
    lds_cp16(A  + (long)(rowA0 + 64 + srow) * lda + k0 + skel, &lA[2048 + w * 512]);
    lds_cp16(Bt + (long)rB1 * ldb + k0 + skel,                 &lB[w * 512]);
    lds_cp16(Bt + (long)rB2 * ldb + k0 + skel,                 &lB[2048 + w * 512]);
    __syncthreads();
    bf16x8 af[4], bfr[4];
    #pragma unroll
    for (int m = 0; m < 4; m++)
      af[m] = *(const bf16x8*)&lA[(wr + m * 16 + lrow) * 32 + kgrp * 8];
    #pragma unroll
    for (int n = 0; n < 4; n++)
      bfr[n] = *(const bf16x8*)&lB[(wc + n * 16 + lrow) * 32 + kgrp * 8];
    #pragma unroll
    for (int m = 0; m < 4; m++)
      #pragma unroll
      for (int n = 0; n < 4; n++)
        acc[m][n] = __builtin_amdgcn_mfma_f32_16x16x32_bf16(af[m], bfr[n], acc[m][n], 0, 0, 0);
    __syncthreads();
  }

  const long coff = (long)(batch / cdiv) * sC2 + (long)(batch % cdiv) * sC;
  #pragma unroll
  for (int m = 0; m < 4; m++) {
    #pragma unroll
    for (int n = 0; n < 4; n++) {
      const int col = rowB0 + wc + n * 16 + lrow;
      #pragma unroll
      for (int j = 0; j < 4; j++) {
        const int row = rowA0 + wr + m * 16 + kgrp * 4 + j;
        if (row < M && col < N) {
          float v = acc[m][n][j];
          if (BIAS) v += bias[col];
          if (RELU) v = fmaxf(v, 0.0f);
          const long off = coff + (long)row * ldc + col;
          if (RESID) v += resid[off];
          if (OUT_BF16) ((u16*)Cv)[off] = f2bf(v);
          else          ((float*)Cv)[off] = v;
        }
      }
    }
  }
}

extern "C" void kernel_launch(void* const* d_in, const int* in_sizes, int n_in,
                              void* d_out, int out_size, void* d_ws, size_t ws_size,
                              hipStream_t stream) {
  constexpr int Lc = 4, Tc = 1024, Dc = 1024, Hc = 16, Fc = 4096, DHc = 64;
  const int M = 2 * Tc;
  const int BIG = 1 << 30;

  const int*   idxp       = (const int*)  d_in[0];
  const float* tok_emb    = (const float*)d_in[1];
  const float* pos_emb    = (const float*)d_in[2];
  const float* Wq         = (const float*)d_in[3];
  const float* bq         = (const float*)d_in[4];
  const float* Wk         = (const float*)d_in[5];
  const float* bk         = (const float*)d_in[6];
  const float* Wv         = (const float*)d_in[7];
  const float* bv         = (const float*)d_in[8];
  const float* Wo         = (const float*)d_in[9];
  const float* bo         = (const float*)d_in[10];
  const float* score_gain = (const float*)d_in[11];
  const float* norm1_gain = (const float*)d_in[12];
  const float* norm2_gain = (const float*)d_in[13];
  const float* W1         = (const float*)d_in[14];
  const float* b1         = (const float*)d_in[15];
  const float* W2         = (const float*)d_in[16];
  const float* b2         = (const float*)d_in[17];
  const float* final_gain = (const float*)d_in[18];
  const float* Wlm        = (const float*)d_in[19];
  const float* blm        = (const float*)d_in[20];

  char* p = (char*)d_ws;
  auto alloc = [&](size_t n) { char* r = p; p += (n + 255) & ~(size_t)255; return r; };
  u16*  wqkv_t = (u16*) alloc((size_t)Lc * 3072 * 1024 * 2);
  u16*  wo_t   = (u16*) alloc((size_t)Lc * 1024 * 1024 * 2);
  u16*  w1_t   = (u16*) alloc((size_t)Lc * 4096 * 1024 * 2);
  u16*  w2_t   = (u16*) alloc((size_t)Lc * 1024 * 4096 * 2);
  u16*  wlm_t  = (u16*) alloc((size_t)32000 * 1024 * 2);
  float* bqkv  = (float*)alloc((size_t)Lc * 3072 * 4);
  float* x     = (float*)alloc((size_t)M * 1024 * 4);
  u16*  hbuf   = (u16*) alloc((size_t)M * 1024 * 2);
  u16*  qkv    = (u16*) alloc((size_t)M * 3072 * 2);
  u16*  v_t    = (u16*) alloc((size_t)2 * Hc * DHc * Tc * 2);
  u16*  obuf   = (u16*) alloc((size_t)M * 1024 * 2);
  u16*  ffh    = (u16*) alloc((size_t)M * 4096 * 2);
  u16*  attn   = (u16*) alloc((size_t)2 * Hc * Tc * Tc * 2);   // both batch elems

  const dim3 tb(32, 8);
  for (int l = 0; l < Lc; l++) {
    wconv_kernel<<<dim3(32, 32), tb, 0, stream>>>(Wq + (size_t)l * Dc * Dc, wqkv_t + ((size_t)l * 3072 + 0) * 1024, 1024, 1024);
    wconv_kernel<<<dim3(32, 32), tb, 0, stream>>>(Wk + (size_t)l * Dc * Dc, wqkv_t + ((size_t)l * 3072 + 1024) * 1024, 1024, 1024);
    wconv_kernel<<<dim3(32, 32), tb, 0, stream>>>(Wv + (size_t)l * Dc * Dc, wqkv_t + ((size_t)l * 3072 + 2048) * 1024, 1024, 1024);
    wconv_kernel<<<dim3(32, 32), tb, 0, stream>>>(Wo + (size_t)l * Dc * Dc, wo_t + (size_t)l * 1024 * 1024, 1024, 1024);
    wconv_kernel<<<dim3(128, 32), tb, 0, stream>>>(W1 + (size_t)l * Dc * Fc, w1_t + (size_t)l * Fc * Dc, 1024, 4096);
    wconv_kernel<<<dim3(32, 128), tb, 0, stream>>>(W2 + (size_t)l * Fc * Dc, w2_t + (size_t)l * Dc * Fc, 4096, 1024);
  }
  wconv_kernel<<<dim3(1000, 32), tb, 0, stream>>>(Wlm, wlm_t, 1024, 32000);
  bias_concat<<<48, 256, 0, stream>>>(bq, bk, bv, bqkv);

  embed_kernel<<<M, 256, 0, stream>>>(idxp, tok_emb, pos_emb, x);

  for (int l = 0; l < Lc; l++) {
    anorm_kernel<<<M, 256, 0, stream>>>(x, norm1_gain + (size_t)l * Dc, hbuf);
    gemm_kernel<true, true, false, false><<<dim3(16 * 24, 1), 256, 0, stream>>>(
        hbuf, 1024, 0, wqkv_t + (size_t)l * 3072 * 1024, 1024, 0,
        qkv, 3072, 0, BIG, 0, bqkv + (size_t)l * 3072, nullptr, M, 3072, 1024, 16);
    build_vt<<<dim3(32, 2, 32), tb, 0, stream>>>(qkv, v_t);

    // fused scores + rational softmax -> attn bf16 (both b, all heads)
    score_kernel<<<dim3(32, 16, 2), 256, 0, stream>>>(qkv, attn, score_gain, l);

    // o[b][q][h*64+dh] = attn[z] @ v_t[z]^T, batched over z = b*16+h
    gemm_kernel<true, false, false, false><<<dim3(8, 32), 256, 0, stream>>>(
        attn, 1024, (long)Tc * Tc, v_t, 1024, (long)DHc * Tc,
        obuf, 1024, DHc, 16, (long)Tc * Dc, nullptr, nullptr, Tc, 64, 1024, 8);

    gemm_kernel<false, true, false, true><<<dim3(16 * 8, 1), 256, 0, stream>>>(
        obuf, 1024, 0, wo_t + (size_t)l * 1024 * 1024, 1024, 0,
        x, 1024, 0, BIG, 0, bo + (size_t)l * 1024, x, M, 1024, 1024, 16);
    anorm_kernel<<<M, 256, 0, stream>>>(x, norm2_gain + (size_t)l * Dc, hbuf);
    gemm_kernel<true, true, true, false><<<dim3(16 * 32, 1), 256, 0, stream>>>(
        hbuf, 1024, 0, w1_t + (size_t)l * Fc * Dc, 1024, 0,
        ffh, 4096, 0, BIG, 0, b1 + (size_t)l * Fc, nullptr, M, 4096, 1024, 16);
    gemm_kernel<false, true, false, true><<<dim3(16 * 8, 1), 256, 0, stream>>>(
        ffh, 4096, 0, w2_t + (size_t)l * Dc * Fc, 4096, 0,
        x, 1024, 0, BIG, 0, b2 + (size_t)l * Dc, x, M, 1024, 4096, 16);
  }

  anorm_kernel<<<M, 256, 0, stream>>>(x, final_gain, hbuf);
  gemm_kernel<false, true, false, false><<<dim3(16 * 250, 1), 256, 0, stream>>>(
      hbuf, 1024, 0, wlm_t, 1024, 0,
      d_out, 32000, 0, BIG, 0, blm, nullptr, M, 32000, 1024, 16);
}

// Round 3
// 1762.159 us; speedup vs baseline: 1.1228x; 1.0951x over previous
//
#include <hip/hip_runtime.h>

typedef unsigned short u16;
typedef __bf16 bf16x8 __attribute__((ext_vector_type(8)));
typedef float f32x4 __attribute__((ext_vector_type(4)));
typedef unsigned int u32;

#define EPSF 1e-6f

__device__ __forceinline__ u16 f2bf(float f) {
  union { float f; unsigned u; } un; un.f = f;
  unsigned r = un.u + 0x7FFFu + ((un.u >> 16) & 1u);
  return (u16)(r >> 16);
}

__device__ __forceinline__ float block_sum(float v) {
  #pragma unroll
  for (int off = 32; off > 0; off >>= 1) v += __shfl_xor(v, off, 64);
  __shared__ float ws[4];
  const int w = threadIdx.x >> 6;
  __syncthreads();
  if ((threadIdx.x & 63) == 0) ws[w] = v;
  __syncthreads();
  return ws[0] + ws[1] + ws[2] + ws[3];
}

// async global->LDS, 16B per lane. LDS dest must be wave-uniform base; HW adds lane*16.
__device__ __forceinline__ void lds_cp16(const void* g, void* l) {
  __builtin_amdgcn_global_load_lds(
      (__attribute__((address_space(1))) void*)g,
      (__attribute__((address_space(3))) void*)l, 16, 0, 0);
}

// ---------------- embedding ----------------
__global__ __launch_bounds__(256) void embed_kernel(
    const int* __restrict__ idx, const float* __restrict__ tok,
    const float* __restrict__ pos, float* __restrict__ x) {
  const int row = blockIdx.x;
  const int tpos = row & 1023;
  const int token = idx[row];
  const int d = threadIdx.x * 4;
  const float4 a = *(const float4*)(tok + (long)token * 1024 + d);
  const float4 b = *(const float4*)(pos + (long)tpos * 1024 + d);
  float4 o; o.x = a.x + b.x; o.y = a.y + b.y; o.z = a.z + b.z; o.w = a.w + b.w;
  *(float4*)(x + (long)row * 1024 + d) = o;
}

// ---------------- anorm ----------------
__global__ __launch_bounds__(256) void anorm_kernel(
    const float* __restrict__ x, const float* __restrict__ gain,
    u16* __restrict__ h) {
  const int row = blockIdx.x;
  const int tid = threadIdx.x;
  const float4 v = *(const float4*)(x + (long)row * 1024 + tid * 4);
  float s = fabsf(v.x) + fabsf(v.y) + fabsf(v.z) + fabsf(v.w);
  s = block_sum(s);
  const float scale = 1.0f / (s * (1.0f / 1024.0f) + EPSF);
  const float4 g = *(const float4*)(gain + tid * 4);
  ushort4 o;
  o.x = f2bf(v.x * g.x * scale);
  o.y = f2bf(v.y * g.y * scale);
  o.z = f2bf(v.z * g.z * scale);
  o.w = f2bf(v.w * g.w * scale);
  *(ushort4*)(h + (long)row * 1024 + tid * 4) = o;
}

// ---- fused scores + rational softmax: one block = 32 q-rows x 1024 cols, one (b,h) ----
__global__ __launch_bounds__(256) void score_kernel(
    const u16* __restrict__ qkv,      // [b][t][3072] bf16
    u16* __restrict__ attn,           // [(b*16+h)][1024][1024] bf16
    const float* __restrict__ score_gain, int l) {
  __shared__ float S[32][1024];       // 128 KiB score panel
  __shared__ u16 kbuf[128 * 64];      // 16 KiB K tile (slot-swizzled)
  __shared__ u16 qbuf[32 * 64];       // 4 KiB Q tile (slot-swizzled)
  const int qt = blockIdx.x, h = blockIdx.y, b = blockIdx.z;
  const int t = threadIdx.x, w = t >> 6, l64 = t & 63;
  const int q0 = qt * 32;
  const u16* Qg = qkv + (size_t)b * 1024 * 3072 + h * 64;
  const u16* Kg = Qg + 1024;

  {
    const int row = t >> 3, slot = t & 7;
    const int gslot = slot ^ (row & 7);
    lds_cp16(Qg + (size_t)(q0 + row) * 3072 + gslot * 8, &qbuf[w * 512]);
  }

  const int lrow = l64 & 15, kgrp = l64 >> 4;
  const int qstripe = (w & 1) * 16, chalf = (w >> 1) * 64;
  const int aswz = lrow & 7;

  for (int ct = 0; ct < 8; ct++) {
    __syncthreads();
    #pragma unroll
    for (int i = 0; i < 4; i++) {
      const int c = i * 256 + t;
      const int row = c >> 3, slot = c & 7;
      const int gslot = slot ^ (row & 7);
      lds_cp16(Kg + (size_t)(ct * 128 + row) * 3072 + gslot * 8,
               &kbuf[(i * 256 + w * 64) * 8]);
    }
    __syncthreads();
    bf16x8 af[2];
    #pragma unroll
    for (int kk = 0; kk < 2; kk++)
      af[kk] = *(const bf16x8*)&qbuf[(qstripe + lrow) * 64 + (((kk << 2) + kgrp) ^ aswz) * 8];
    #pragma unroll
    for (int n = 0; n < 4; n++) {
      f32x4 acc = {0.f, 0.f, 0.f, 0.f};
      #pragma unroll
      for (int kk = 0; kk < 2; kk++) {
        const bf16x8 bf = *(const bf16x8*)&kbuf[(chalf + n * 16 + lrow) * 64 +
                                                (((kk << 2) + kgrp) ^ aswz) * 8];
        acc = __builtin_amdgcn_mfma_f32_16x16x32_bf16(af[kk], bf, acc, 0, 0, 0);
      }
      const int col = ct * 128 + chalf + n * 16 + lrow;
      #pragma unroll
      for (int j = 0; j < 4; j++)
        S[qstripe + kgrp * 4 + j][col] = acc[j];
    }
  }
  __syncthreads();

  const float gain = score_gain[l];
  u16* arow_base = attn + ((size_t)(b * 16 + h) * 1024 + q0) * 1024;
  #pragma unroll 1
  for (int r = 0; r < 8; r++) {
    const int row = w * 8 + r;
    const int qglob = q0 + row;
    float s = 0.f;
    #pragma unroll
    for (int i = 0; i < 8; i++) {
      const float2 v = *(const float2*)&S[row][l64 * 2 + i * 128];
      s += v.x + v.y;
    }
    #pragma unroll
    for (int off = 32; off; off >>= 1) s += __shfl_xor(s, off, 64);
    const float mean = s * (1.0f / 1024.0f);
    float a = 0.f;
    #pragma unroll
    for (int i = 0; i < 8; i++) {
      const float2 v = *(const float2*)&S[row][l64 * 2 + i * 128];
      a += fabsf(v.x - mean) + fabsf(v.y - mean);
    }
    #pragma unroll
    for (int off = 32; off; off >>= 1) a += __shfl_xor(a, off, 64);
    const float gs = gain / (a * (1.0f / 1024.0f) + EPSF);
    float ps = 0.f;
    #pragma unroll
    for (int i = 0; i < 8; i++) {
      const int cp = l64 * 2 + i * 128;
      float2 v = *(const float2*)&S[row][cp];
      float sv0 = (v.x - mean) * gs;
      float sv1 = (v.y - mean) * gs;
      if (cp > qglob)     sv0 = -1000.0f;
      if (cp + 1 > qglob) sv1 = -1000.0f;
      const float r0 = sv0 / (fabsf(sv0) + 1.0f);
      const float r1 = sv1 / (fabsf(sv1) + 1.0f);
      const float a0 = (r0 + 1.0f) * 0.5f, a1 = (r1 + 1.0f) * 0.5f;
      const float b0 = a0 * a0, b1 = a1 * a1;
      float2 pv; pv.x = b0 * b0; pv.y = b1 * b1;
      *(float2*)&S[row][cp] = pv;
      ps += pv.x + pv.y;
    }
    #pragma unroll
    for (int off = 32; off; off >>= 1) ps += __shfl_xor(ps, off, 64);
    const float inv = 1.0f / (ps + EPSF);
    u16* arow = arow_base + (size_t)row * 1024;
    #pragma unroll
    for (int i = 0; i < 8; i++) {
      const int cp = l64 * 2 + i * 128;
      const float2 v = *(const float2*)&S[row][cp];
      const u32 packed = (u32)f2bf(v.x * inv) | ((u32)f2bf(v.y * inv) << 16);
      *(u32*)&arow[cp] = packed;
    }
  }
}

// ---------------- weight convert: dst[c][r] = bf16(src[r][c]) ----------------
__global__ __launch_bounds__(256) void wconv_kernel(
    const float* __restrict__ src, u16* __restrict__ dst, int R, int C) {
  __shared__ float tile[32][33];
  const int c0 = blockIdx.x * 32, r0 = blockIdx.y * 32;
  const int tx = threadIdx.x, ty = threadIdx.y;
  #pragma unroll
  for (int i = 0; i < 4; i++)
    tile[ty + 8 * i][tx] = src[(long)(r0 + ty + 8 * i) * C + c0 + tx];
  __syncthreads();
  #pragma unroll
  for (int i = 0; i < 4; i++)
    dst[(long)(c0 + ty + 8 * i) * R + r0 + tx] = f2bf(tile[tx][ty + 8 * i]);
}

// ---------------- v_t[(b*16+h)][dh][t] ----------------
__global__ __launch_bounds__(256) void build_vt(
    const u16* __restrict__ qkv, u16* __restrict__ v_t) {
  __shared__ u16 tile[32][33];
  const int z = blockIdx.z, b = z >> 4, h = z & 15;
  const u16* src = qkv + (long)b * 1024 * 3072 + 2048 + h * 64;
  u16* dst = v_t + (long)z * 64 * 1024;
  const int t0 = blockIdx.x * 32, d0 = blockIdx.y * 32;
  const int tx = threadIdx.x, ty = threadIdx.y;
  #pragma unroll
  for (int i = 0; i < 4; i++)
    tile[ty + 8 * i][tx] = src[(long)(t0 + ty + 8 * i) * 3072 + d0 + tx];
  __syncthreads();
  #pragma unroll
  for (int i = 0; i < 4; i++)
    dst[(long)(d0 + ty + 8 * i) * 1024 + t0 + tx] = tile[tx][ty + 8 * i];
}

__global__ __launch_bounds__(256) void bias_concat(
    const float* __restrict__ bq, const float* __restrict__ bk,
    const float* __restrict__ bv, float* __restrict__ out) {
  const int i = blockIdx.x * 256 + threadIdx.x;
  const int l = i / 3072, j = i % 3072;
  float v;
  if (j < 1024)      v = bq[l * 1024 + j];
  else if (j < 2048) v = bk[l * 1024 + j - 1024];
  else               v = bv[l * 1024 + j - 2048];
  out[i] = v;
}

// =====================================================================
// 256x256-tile deep-pipelined GEMM: C = A[M,K] @ Bt[N,K]^T
// 8 waves (2Mx4N), BK=32, 4-deep LDS ring (128 KiB), counted vmcnt,
// XOR-swizzled LDS (pre-swizzled global source, rule #21), setprio MFMA.
// Requires M%256==0, N%256==0, K%32==0, K>=96.
// =====================================================================
template <bool OUT_BF16, bool BIAS, bool RELU, bool RESID>
__global__ __launch_bounds__(512) void gemm256_kernel(
    const u16* __restrict__ A, long lda,
    const u16* __restrict__ Bt, long ldb,
    void* __restrict__ Cv, long ldc,
    const float* __restrict__ bias, const float* __restrict__ resid,
    int M, int N, int K, int nTM) {
  __shared__ u16 lds[65536];          // 4 bufs x (A 8192 + B 8192) u16
  // bijective XCD swizzle + tm-fast decode
  const int nwg = gridDim.x;
  const int qx = nwg >> 3, rx = nwg & 7;
  const int xcd = blockIdx.x & 7, seq = blockIdx.x >> 3;
  const int wg = (xcd < rx ? xcd * (qx + 1) : rx * (qx + 1) + (xcd - rx) * qx) + seq;
  const int tm = wg % nTM, tn = wg / nTM;
  const int rowA0 = tm * 256, rowB0 = tn * 256;

  const int t = threadIdx.x, w = t >> 6, l = t & 63;
  const int lrow = l & 15, kgrp = l >> 4;
  const int wr = w >> 2, wc = w & 3;            // wave grid 2M x 4N

  // staging: thread t handles chunk row=t>>2, slot=t&3 of each 128-row round;
  // global source slot pre-swizzled so LDS stays linear (rule #21)
  const int srow = t >> 2;
  const int scol = ((t & 3) ^ ((t >> 3) & 3)) * 8;
  const u16* Asrc = A + (long)(rowA0 + srow) * lda + scol;
  const u16* Bsrc = Bt + (long)(rowB0 + srow) * ldb + scol;
  char* ldsB = (char*)lds;
  const int wbase = w * 1024;                   // per-wave byte chunk in each round

  // frag read offsets (elements), swizzle slot = kgrp ^ ((row>>1)&3)
  const int fswz = (kgrp ^ ((lrow >> 1) & 3)) * 8;
  const int aoff = (wr * 128 + lrow) * 32 + fswz;
  const int boff = 8192 + (wc * 64 + lrow) * 32 + fswz;

  f32x4 acc[8][4] = {};
  const int NT = K >> 5;

  // prologue: stage tiles 0,1,2 (4 gloads/thread each)
  #pragma unroll
  for (int pt = 0; pt < 3; pt++) {
    const int k0 = pt << 5;
    const int bb = pt * 32768;
    lds_cp16(Asrc + k0,                    ldsB + bb + wbase);
    lds_cp16(Asrc + (long)128 * lda + k0,  ldsB + bb + 8192 + wbase);
    lds_cp16(Bsrc + k0,                    ldsB + bb + 16384 + wbase);
    lds_cp16(Bsrc + (long)128 * ldb + k0,  ldsB + bb + 24576 + wbase);
  }

  for (int tt = 0; tt < NT; tt++) {
    // wait for tile tt (own wave's loads), then collective barrier
    const int rem = NT - 1 - tt;
    if (rem >= 2)      asm volatile("s_waitcnt vmcnt(8)" ::: "memory");
    else if (rem == 1) asm volatile("s_waitcnt vmcnt(4)" ::: "memory");
    else               asm volatile("s_waitcnt vmcnt(0)" ::: "memory");
    __builtin_amdgcn_sched_barrier(0);
    __builtin_amdgcn_s_barrier();

    const u16* buf = lds + (tt & 3) * 16384;
    const int stage = tt + 3 < NT;
    const int k0n = (tt + 3) << 5;
    const int bbn = ((tt + 3) & 3) * 32768;

    // ---- phase A: ds_read A m0-3 + B n0-3 ; stage next-tile A ----
    bf16x8 aF[4], bF[4];
    #pragma unroll
    for (int m = 0; m < 4; m++) aF[m] = *(const bf16x8*)(buf + aoff + m * 512);
    #pragma unroll
    for (int n = 0; n < 4; n++) bF[n] = *(const bf16x8*)(buf + boff + n * 512);
    if (stage) {
      lds_cp16(Asrc + k0n,                   ldsB + bbn + wbase);
      lds_cp16(Asrc + (long)128 * lda + k0n, ldsB + bbn + 8192 + wbase);
    }
    asm volatile("s_waitcnt lgkmcnt(0)" ::: "memory");
    __builtin_amdgcn_sched_barrier(0);
    __builtin_amdgcn_s_setprio(1);
    #pragma unroll
    for (int m = 0; m < 4; m++)
      #pragma unroll
      for (int n = 0; n < 4; n++)
        acc[m][n] = __builtin_amdgcn_mfma_f32_16x16x32_bf16(aF[m], bF[n], acc[m][n], 0, 0, 0);
    __builtin_amdgcn_s_setprio(0);

    // ---- phase B: ds_read A m4-7 ; stage next-tile B ----
    #pragma unroll
    for (int m = 0; m < 4; m++) aF[m] = *(const bf16x8*)(buf + aoff + (m + 4) * 512);
    if (stage) {
      lds_cp16(Bsrc + k0n,                   ldsB + bbn + 16384 + wbase);
      lds_cp16(Bsrc + (long)128 * ldb + k0n, ldsB + bbn + 24576 + wbase);
    }
    asm volatile("s_waitcnt lgkmcnt(0)" ::: "memory");
    __builtin_amdgcn_sched_barrier(0);
    __builtin_amdgcn_s_setprio(1);
    #pragma unroll
    for (int m = 0; m < 4; m++)
      #pragma unroll
      for (int n = 0; n < 4; n++)
        acc[m + 4][n] = __builtin_amdgcn_mfma_f32_16x16x32_bf16(aF[m], bF[n], acc[m + 4][n], 0, 0, 0);
    __builtin_amdgcn_s_setprio(0);
  }

  // ---- epilogue ----
  float bv[4];
  #pragma unroll
  for (int n = 0; n < 4; n++)
    bv[n] = BIAS ? bias[rowB0 + wc * 64 + n * 16 + lrow] : 0.0f;
  #pragma unroll
  for (int m = 0; m < 8; m++) {
    const int row = rowA0 + wr * 128 + m * 16 + kgrp * 4;
    #pragma unroll
    for (int n = 0; n < 4; n++) {
      const int col = rowB0 + wc * 64 + n * 16 + lrow;
      #pragma unroll
      for (int j = 0; j < 4; j++) {
        float v = acc[m][n][j] + bv[n];
        if (RELU) v = fmaxf(v, 0.0f);
        const long off = (long)(row + j) * ldc + col;
        if (RESID) v += resid[off];
        if (OUT_BF16) ((u16*)Cv)[off] = f2bf(v);
        else          ((float*)Cv)[off] = v;
      }
    }
  }
}

// ---------------- generic 128x128 bf16 MFMA GEMM (kept for small/batched) ----------------
template <bool OUT_BF16, bool BIAS, bool RELU, bool RESID>
__global__ __launch_bounds__(256) void gemm_kernel(
    const u16* __restrict__ A, long lda, long sA,
    const u16* __restrict__ Bt, long ldb, long sB,
    void* __restrict__ Cv, long ldc, long sC, int cdiv, long sC2,
    const float* __restrict__ bias, const float* __restrict__ resid,
    int M, int N, int K, int nTM) {
  __shared__ u16 lA[128 * 32];
  __shared__ u16 lB[128 * 32];
  const int nwg = gridDim.x;
  const int qx = nwg >> 3, rx = nwg & 7;
  const int xcd = blockIdx.x & 7, seq = blockIdx.x >> 3;
  const int wg = (xcd < rx ? xcd * (qx + 1) : rx * (qx + 1) + (xcd - rx) * qx) + seq;
  const int tm = wg % nTM, tn = wg / nTM;
  const int batch = blockIdx.y;
  const int t = threadIdx.x, w = t >> 6, l = t & 63;
  A  += (long)batch * sA;
  Bt += (long)batch * sB;
  const int rowA0 = tm * 128, rowB0 = tn * 128;
  const int srow = (w << 4) + (l >> 2);
  const int skel = (l & 3) << 3;
  const int wr = (w >> 1) << 6, wc = (w & 1) << 6;
  const int lrow = l & 15, kgrp = l >> 4;
  f32x4 acc[4][4] = {};

  for (int k0 = 0; k0 < K; k0 += 32) {
    int rB1 = rowB0 + srow;      if (rB1 >= N) rB1 = N - 1;
    int rB2 = rowB0 + 64 + srow; if (rB2 >= N) rB2 = N - 1;
    lds_cp16(A  + (long)(rowA0 + srow) * lda + k0 + skel,      &lA[w * 512]);
    lds_cp16(A  + (long)(rowA0 + 64 + srow) * lda + k0 + skel, &lA[2048 + w * 512]);
    lds_cp16(Bt + (long)rB1 * ldb + k0 + skel,                 &lB[w * 512]);
    lds_cp16(Bt + (long)rB2 * ldb + k0 + skel,                 &lB[2048 + w * 512]);
    __syncthreads();
    bf16x8 af[4], bfr[4];
    #pragma unroll
    for (int m = 0; m < 4; m++)
      af[m] = *(const bf16x8*)&lA[(wr + m * 16 + lrow) * 32 + kgrp * 8];
    #pragma unroll
    for (int n = 0; n < 4; n++)
      bfr[n] = *(const bf16x8*)&lB[(wc + n * 16 + lrow) * 32 + kgrp * 8];
    #pragma unroll
    for (int m = 0; m < 4; m++)
      #pragma unroll
      for (int n = 0; n < 4; n++)
        acc[m][n] = __builtin_amdgcn_mfma_f32_16x16x32_bf16(af[m], bfr[n], acc[m][n], 0, 0, 0);
    __syncthreads();
  }

  const long coff = (long)(batch / cdiv) * sC2 + (long)(batch % cdiv) * sC;
  #pragma unroll
  for (int m = 0; m < 4; m++) {
    #pragma unroll
    for (int n = 0; n < 4; n++) {
      const int col = rowB0 + wc + n * 16 + lrow;
      #pragma unroll
      for (int j = 0; j < 4; j++) {
        const int row = rowA0 + wr + m * 16 + kgrp * 4 + j;
        if (row < M && col < N) {
          float v = acc[m][n][j];
          if (BIAS) v += bias[col];
          if (RELU) v = fmaxf(v, 0.0f);
          const long off = coff + (long)row * ldc + col;
          if (RESID) v += resid[off];
          if (OUT_BF16) ((u16*)Cv)[off] = f2bf(v);
          else          ((float*)Cv)[off] = v;
        }
      }
    }
  }
}

extern "C" void kernel_launch(void* const* d_in, const int* in_sizes, int n_in,
                              void* d_out, int out_size, void* d_ws, size_t ws_size,
                              hipStream_t stream) {
  constexpr int Lc = 4, Tc = 1024, Dc = 1024, Hc = 16, Fc = 4096, DHc = 64;
  const int M = 2 * Tc;
  const int BIG = 1 << 30;

  const int*   idxp       = (const int*)  d_in[0];
  const float* tok_emb    = (const float*)d_in[1];
  const float* pos_emb    = (const float*)d_in[2];
  const float* Wq         = (const float*)d_in[3];
  const float* bq         = (const float*)d_in[4];
  const float* Wk         = (const float*)d_in[5];
  const float* bk         = (const float*)d_in[6];
  const float* Wv         = (const float*)d_in[7];
  const float* bv         = (const float*)d_in[8];
  const float* Wo         = (const float*)d_in[9];
  const float* bo         = (const float*)d_in[10];
  const float* score_gain = (const float*)d_in[11];
  const float* norm1_gain = (const float*)d_in[12];
  const float* norm2_gain = (const float*)d_in[13];
  const float* W1         = (const float*)d_in[14];
  const float* b1         = (const float*)d_in[15];
  const float* W2         = (const float*)d_in[16];
  const float* b2         = (const float*)d_in[17];
  const float* final_gain = (const float*)d_in[18];
  const float* Wlm        = (const float*)d_in[19];
  const float* blm        = (const float*)d_in[20];

  char* p = (char*)d_ws;
  auto alloc = [&](size_t n) { char* r = p; p += (n + 255) & ~(size_t)255; return r; };
  u16*  wqkv_t = (u16*) alloc((size_t)Lc * 3072 * 1024 * 2);
  u16*  wo_t   = (u16*) alloc((size_t)Lc * 1024 * 1024 * 2);
  u16*  w1_t   = (u16*) alloc((size_t)Lc * 4096 * 1024 * 2);
  u16*  w2_t   = (u16*) alloc((size_t)Lc * 1024 * 4096 * 2);
  u16*  wlm_t  = (u16*) alloc((size_t)32000 * 1024 * 2);
  float* bqkv  = (float*)alloc((size_t)Lc * 3072 * 4);
  float* x     = (float*)alloc((size_t)M * 1024 * 4);
  u16*  hbuf   = (u16*) alloc((size_t)M * 1024 * 2);
  u16*  qkv    = (u16*) alloc((size_t)M * 3072 * 2);
  u16*  v_t    = (u16*) alloc((size_t)2 * Hc * DHc * Tc * 2);
  u16*  obuf   = (u16*) alloc((size_t)M * 1024 * 2);
  u16*  ffh    = (u16*) alloc((size_t)M * 4096 * 2);
  u16*  attn   = (u16*) alloc((size_t)2 * Hc * Tc * Tc * 2);

  const dim3 tb(32, 8);
  for (int l = 0; l < Lc; l++) {
    wconv_kernel<<<dim3(32, 32), tb, 0, stream>>>(Wq + (size_t)l * Dc * Dc, wqkv_t + ((size_t)l * 3072 + 0) * 1024, 1024, 1024);
    wconv_kernel<<<dim3(32, 32), tb, 0, stream>>>(Wk + (size_t)l * Dc * Dc, wqkv_t + ((size_t)l * 3072 + 1024) * 1024, 1024, 1024);
    wconv_kernel<<<dim3(32, 32), tb, 0, stream>>>(Wv + (size_t)l * Dc * Dc, wqkv_t + ((size_t)l * 3072 + 2048) * 1024, 1024, 1024);
    wconv_kernel<<<dim3(32, 32), tb, 0, stream>>>(Wo + (size_t)l * Dc * Dc, wo_t + (size_t)l * 1024 * 1024, 1024, 1024);
    wconv_kernel<<<dim3(128, 32), tb, 0, stream>>>(W1 + (size_t)l * Dc * Fc, w1_t + (size_t)l * Fc * Dc, 1024, 4096);
    wconv_kernel<<<dim3(32, 128), tb, 0, stream>>>(W2 + (size_t)l * Fc * Dc, w2_t + (size_t)l * Dc * Fc, 4096, 1024);
  }
  wconv_kernel<<<dim3(1000, 32), tb, 0, stream>>>(Wlm, wlm_t, 1024, 32000);
  bias_concat<<<48, 256, 0, stream>>>(bq, bk, bv, bqkv);

  embed_kernel<<<M, 256, 0, stream>>>(idxp, tok_emb, pos_emb, x);

  for (int l = 0; l < Lc; l++) {
    anorm_kernel<<<M, 256, 0, stream>>>(x, norm1_gain + (size_t)l * Dc, hbuf);
    gemm_kernel<true, true, false, false><<<dim3(16 * 24, 1), 256, 0, stream>>>(
        hbuf, 1024, 0, wqkv_t + (size_t)l * 3072 * 1024, 1024, 0,
        qkv, 3072, 0, BIG, 0, bqkv + (size_t)l * 3072, nullptr, M, 3072, 1024, 16);
    build_vt<<<dim3(32, 2, 32), tb, 0, stream>>>(qkv, v_t);

    score_kernel<<<dim3(32, 16, 2), 256, 0, stream>>>(qkv, attn, score_gain, l);

    gemm_kernel<true, false, false, false><<<dim3(8, 32), 256, 0, stream>>>(
        attn, 1024, (long)Tc * Tc, v_t, 1024, (long)DHc * Tc,
        obuf, 1024, DHc, 16, (long)Tc * Dc, nullptr, nullptr, Tc, 64, 1024, 8);

    gemm_kernel<false, true, false, true><<<dim3(16 * 8, 1), 256, 0, stream>>>(
        obuf, 1024, 0, wo_t + (size_t)l * 1024 * 1024, 1024, 0,
        x, 1024, 0, BIG, 0, bo + (size_t)l * 1024, x, M, 1024, 1024, 16);
    anorm_kernel<<<M, 256, 0, stream>>>(x, norm2_gain + (size_t)l * Dc, hbuf);
    // FFN1 on the 256x256 pipelined kernel: grid 8 x 16 = 128
    gemm256_kernel<true, true, true, false><<<dim3(128), 512, 0, stream>>>(
        hbuf, 1024, w1_t + (size_t)l * Fc * Dc, 1024,
        ffh, 4096, b1 + (size_t)l * Fc, nullptr, M, 4096, 1024, 8);
    gemm_kernel<false, true, false, true><<<dim3(16 * 8, 1), 256, 0, stream>>>(
        ffh, 4096, 0, w2_t + (size_t)l * Dc * Fc, 4096, 0,
        x, 1024, 0, BIG, 0, b2 + (size_t)l * Dc, x, M, 1024, 4096, 16);
  }

  anorm_kernel<<<M, 256, 0, stream>>>(x, final_gain, hbuf);
  // LM head on the 256x256 pipelined kernel: grid 8 x 125 = 1000
  gemm256_kernel<false, true, false, false><<<dim3(1000), 512, 0, stream>>>(
      hbuf, 1024, wlm_t, 1024,
      d_out, 32000, blm, nullptr, M, 32000, 1024, 8);
}

// Round 4
// 1569.966 us; speedup vs baseline: 1.2602x; 1.1224x over previous
//
#include <hip/hip_runtime.h>

typedef unsigned short u16;
typedef __bf16 bf16x8 __attribute__((ext_vector_type(8)));
typedef float f32x4 __attribute__((ext_vector_type(4)));
typedef unsigned int u32;

#define EPSF 1e-6f

__device__ __forceinline__ u16 f2bf(float f) {
  union { float f; unsigned u; } un; un.f = f;
  unsigned r = un.u + 0x7FFFu + ((un.u >> 16) & 1u);
  return (u16)(r >> 16);
}
__device__ __forceinline__ float bf2f(u16 v) {
  union { u32 u; float f; } un; un.u = ((u32)v) << 16; return un.f;
}

__device__ __forceinline__ float block_sum(float v) {
  #pragma unroll
  for (int off = 32; off > 0; off >>= 1) v += __shfl_xor(v, off, 64);
  __shared__ float ws[4];
  const int w = threadIdx.x >> 6;
  __syncthreads();
  if ((threadIdx.x & 63) == 0) ws[w] = v;
  __syncthreads();
  return ws[0] + ws[1] + ws[2] + ws[3];
}

// async global->LDS, 16B per lane. LDS dest must be wave-uniform base; HW adds lane*16.
__device__ __forceinline__ void lds_cp16(const void* g, void* l) {
  __builtin_amdgcn_global_load_lds(
      (__attribute__((address_space(1))) void*)g,
      (__attribute__((address_space(3))) void*)l, 16, 0, 0);
}

// ---------------- embedding ----------------
__global__ __launch_bounds__(256) void embed_kernel(
    const int* __restrict__ idx, const float* __restrict__ tok,
    const float* __restrict__ pos, float* __restrict__ x) {
  const int row = blockIdx.x;
  const int tpos = row & 1023;
  const int token = idx[row];
  const int d = threadIdx.x * 4;
  const float4 a = *(const float4*)(tok + (long)token * 1024 + d);
  const float4 b = *(const float4*)(pos + (long)tpos * 1024 + d);
  float4 o; o.x = a.x + b.x; o.y = a.y + b.y; o.z = a.z + b.z; o.w = a.w + b.w;
  *(float4*)(x + (long)row * 1024 + d) = o;
}

// ---------------- anorm ----------------
__global__ __launch_bounds__(256) void anorm_kernel(
    const float* __restrict__ x, const float* __restrict__ gain,
    u16* __restrict__ h) {
  const int row = blockIdx.x;
  const int tid = threadIdx.x;
  const float4 v = *(const float4*)(x + (long)row * 1024 + tid * 4);
  float s = fabsf(v.x) + fabsf(v.y) + fabsf(v.z) + fabsf(v.w);
  s = block_sum(s);
  const float scale = 1.0f / (s * (1.0f / 1024.0f) + EPSF);
  const float4 g = *(const float4*)(gain + tid * 4);
  ushort4 o;
  o.x = f2bf(v.x * g.x * scale);
  o.y = f2bf(v.y * g.y * scale);
  o.z = f2bf(v.z * g.z * scale);
  o.w = f2bf(v.w * g.w * scale);
  *(ushort4*)(h + (long)row * 1024 + tid * 4) = o;
}

// =====================================================================
// Fused attention: scores (QK^T) + rational softmax + PV, one block per
// (b, h, 32 q-rows). 4 waves. S panel bf16 chunk-swizzled in LDS (64KB);
// K/V stream through a 2-slot 8KB ring with counted vmcnt + raw barriers.
// LDS total 80 KB -> 2 blocks/CU.
// =====================================================================
__global__ __launch_bounds__(256) void attn_fused_kernel(
    const u16* __restrict__ qkv,      // [b][t][3072] bf16
    const u16* __restrict__ v_t,      // [(b*16+h)][64][1024] bf16
    u16* __restrict__ obuf,           // [b*1024+t][1024] bf16
    const float* __restrict__ score_gain, int l) {
  __shared__ u16 Sb[32 * 1024];       // 64 KB score/P panel (swizzled chunks)
  __shared__ u16 kv[2][64 * 64];      // 2 x 8 KB K/V tile ring (swizzled chunks)
  const int qt = blockIdx.x, h = blockIdx.y, b = blockIdx.z;
  const int tid = threadIdx.x, w = tid >> 6, l64 = tid & 63;
  const int q0 = qt * 32;
  const u16* Qg = qkv + (size_t)b * (1024 * 3072) + h * 64;
  const u16* Kg = Qg + 1024;
  const u16* Vt = v_t + (size_t)(b * 16 + h) * (64 * 1024);

  const int lrow = l64 & 15, kgrp = l64 >> 4;
  const int qstripe = (w & 1) << 4;   // 0 / 16 (q rows)
  const int npair = (w >> 1) << 1;    // 0 / 2  (col-frag base)

  // S element index (u16 units): row-major rows of 1024, chunk-of-8 XOR row&7
  auto sidx = [](int row, int t) {
    return (row << 10) + ((((t >> 3) ^ (row & 7)) << 3) | (t & 7));
  };

  // ---- staging helpers (rule #21: linear LDS dest, pre-swizzled global src) ----
  auto stageK = [&](int ct, int s) {
    #pragma unroll
    for (int i = 0; i < 2; i++) {
      const int cl = i * 256 + tid;
      const int row = cl >> 3, slot = cl & 7;
      lds_cp16(Kg + (size_t)((ct << 6) + row) * 3072 + ((slot ^ (row & 7)) << 3),
               (char*)kv + s * 8192 + i * 4096 + (w << 10));
    }
  };
  auto stageV = [&](int vt, int s) {
    #pragma unroll
    for (int i = 0; i < 2; i++) {
      const int cl = i * 256 + tid;
      const int row = cl >> 3, slot = cl & 7;   // row = dh
      lds_cp16(Vt + ((size_t)row << 10) + (vt << 6) + ((slot ^ (row & 7)) << 3),
               (char*)kv + s * 8192 + i * 4096 + (w << 10));
    }
  };

  // ---- prologue: stage Q (into S area temporarily), K0, K1 ----
  {
    const int row = tid >> 3, slot = tid & 7;
    lds_cp16(Qg + (size_t)(q0 + row) * 3072 + ((slot ^ (row & 7)) << 3),
             (char*)Sb + (w << 10));
  }
  stageK(0, 0);
  stageK(1, 1);
  asm volatile("s_waitcnt vmcnt(4)" ::: "memory");   // Q done; K0,K1 in flight
  __builtin_amdgcn_sched_barrier(0);
  __builtin_amdgcn_s_barrier();
  bf16x8 qf[2];
  {
    const int row = qstripe + lrow;
    #pragma unroll
    for (int kk = 0; kk < 2; kk++)
      qf[kk] = *(const bf16x8*)&Sb[(row << 6) + ((((kk << 2) + kgrp) ^ (row & 7)) << 3)];
  }
  asm volatile("s_waitcnt lgkmcnt(0)" ::: "memory");
  __builtin_amdgcn_sched_barrier(0);

  const float gain = score_gain[l];

  // ---- QK^T: 16 tiles of 64 cols ----
  #pragma unroll 2
  for (int ct = 0; ct < 16; ct++) {
    asm volatile("s_waitcnt vmcnt(2)" ::: "memory");  // tile ct ready (ct+1 in flight)
    __builtin_amdgcn_sched_barrier(0);
    __builtin_amdgcn_s_barrier();
    const u16* kb = kv[ct & 1];
    bf16x8 bF[2][2];
    #pragma unroll
    for (int nn = 0; nn < 2; nn++) {
      const int row = ((npair + nn) << 4) + lrow;     // t-local
      #pragma unroll
      for (int kk = 0; kk < 2; kk++)
        bF[nn][kk] = *(const bf16x8*)&kb[(row << 6) + ((((kk << 2) + kgrp) ^ (row & 7)) << 3)];
    }
    asm volatile("s_waitcnt lgkmcnt(0)" ::: "memory");
    __builtin_amdgcn_sched_barrier(0);
    __builtin_amdgcn_s_barrier();                     // all waves done reading slot
    if (ct < 14)      stageK(ct + 2, ct & 1);
    else if (ct == 14) stageV(0, 0);
    else               stageV(1, 1);
    f32x4 accs[2] = {};
    __builtin_amdgcn_s_setprio(1);
    #pragma unroll
    for (int nn = 0; nn < 2; nn++)
      #pragma unroll
      for (int kk = 0; kk < 2; kk++)
        accs[nn] = __builtin_amdgcn_mfma_f32_16x16x32_bf16(qf[kk], bF[nn][kk], accs[nn], 0, 0, 0);
    __builtin_amdgcn_s_setprio(0);
    #pragma unroll
    for (int nn = 0; nn < 2; nn++) {
      const int col = (ct << 6) + ((npair + nn) << 4) + lrow;
      #pragma unroll
      for (int j = 0; j < 4; j++) {
        const int row = qstripe + (kgrp << 2) + j;
        Sb[sidx(row, col)] = f2bf(accs[nn][j]);
      }
    }
  }
  __syncthreads();

  // ---- per-row stats + rational softmax (wave w owns rows 8w..8w+7) ----
  #pragma unroll 1
  for (int r = 0; r < 8; r++) {
    const int row = (w << 3) + r;
    const int qglob = q0 + row;
    float sreg[16], p[16];
    float ssum = 0.f;
    #pragma unroll
    for (int i = 0; i < 8; i++) {
      const int t = (l64 << 1) + (i << 7);
      const u32 v = *(const u32*)&Sb[sidx(row, t)];
      sreg[2 * i]     = bf2f((u16)(v & 0xffff));
      sreg[2 * i + 1] = bf2f((u16)(v >> 16));
      ssum += sreg[2 * i] + sreg[2 * i + 1];
    }
    #pragma unroll
    for (int off = 32; off; off >>= 1) ssum += __shfl_xor(ssum, off, 64);
    const float mean = ssum * (1.0f / 1024.0f);
    float asum = 0.f;
    #pragma unroll
    for (int i = 0; i < 16; i++) asum += fabsf(sreg[i] - mean);
    #pragma unroll
    for (int off = 32; off; off >>= 1) asum += __shfl_xor(asum, off, 64);
    const float gs = gain / (asum * (1.0f / 1024.0f) + EPSF);
    float ps = 0.f;
    #pragma unroll
    for (int i = 0; i < 8; i++) {
      #pragma unroll
      for (int u = 0; u < 2; u++) {
        const int t = (l64 << 1) + (i << 7) + u;
        float sv = (sreg[2 * i + u] - mean) * gs;
        if (t > qglob) sv = -1000.0f;
        const float rr = sv / (fabsf(sv) + 1.0f);
        const float a1 = (rr + 1.0f) * 0.5f;
        const float a2 = a1 * a1;
        p[2 * i + u] = a2 * a2;
        ps += p[2 * i + u];
      }
    }
    #pragma unroll
    for (int off = 32; off; off >>= 1) ps += __shfl_xor(ps, off, 64);
    const float inv = 1.0f / (ps + EPSF);
    #pragma unroll
    for (int i = 0; i < 8; i++) {
      const int t = (l64 << 1) + (i << 7);
      const u32 packed = (u32)f2bf(p[2 * i] * inv) | ((u32)f2bf(p[2 * i + 1] * inv) << 16);
      *(u32*)&Sb[sidx(row, t)] = packed;
    }
  }
  __syncthreads();

  // ---- PV: O[32][64] = P @ V, streaming 16 V-tiles of 64 t-rows ----
  f32x4 aco[2] = {};
  #pragma unroll 2
  for (int vt = 0; vt < 16; vt++) {
    if (vt < 15) asm volatile("s_waitcnt vmcnt(2)" ::: "memory");
    else         asm volatile("s_waitcnt vmcnt(0)" ::: "memory");
    __builtin_amdgcn_sched_barrier(0);
    __builtin_amdgcn_s_barrier();
    const u16* vb = kv[vt & 1];
    bf16x8 aF[2], bFv[2][2];
    {
      const int row = qstripe + lrow;
      #pragma unroll
      for (int ks = 0; ks < 2; ks++) {
        const int t = (vt << 6) + (ks << 5) + (kgrp << 3);
        aF[ks] = *(const bf16x8*)&Sb[(row << 10) + ((((t >> 3) ^ (row & 7)) << 3))];
      }
    }
    #pragma unroll
    for (int nf = 0; nf < 2; nf++) {
      const int dh = ((npair + nf) << 4) + lrow;
      #pragma unroll
      for (int ks = 0; ks < 2; ks++)
        bFv[nf][ks] = *(const bf16x8*)&vb[(dh << 6) + ((((ks << 2) + kgrp) ^ (dh & 7)) << 3)];
    }
    asm volatile("s_waitcnt lgkmcnt(0)" ::: "memory");
    __builtin_amdgcn_sched_barrier(0);
    __builtin_amdgcn_s_barrier();
    if (vt < 14) stageV(vt + 2, vt & 1);
    __builtin_amdgcn_s_setprio(1);
    #pragma unroll
    for (int nf = 0; nf < 2; nf++)
      #pragma unroll
      for (int ks = 0; ks < 2; ks++)
        aco[nf] = __builtin_amdgcn_mfma_f32_16x16x32_bf16(aF[ks], bFv[nf][ks], aco[nf], 0, 0, 0);
    __builtin_amdgcn_s_setprio(0);
  }

  // ---- epilogue: O -> obuf[b*1024+q][h*64+dh] ----
  u16* Ob = obuf + ((size_t)((b << 10) + q0 + qstripe + (kgrp << 2)) << 10) + (h << 6);
  #pragma unroll
  for (int nf = 0; nf < 2; nf++) {
    const int dh = ((npair + nf) << 4) + lrow;
    #pragma unroll
    for (int j = 0; j < 4; j++)
      Ob[(size_t)j << 10 | dh] = f2bf(aco[nf][j]);
  }
}

// ---------------- weight convert: dst[c][r] = bf16(src[r][c]) ----------------
__global__ __launch_bounds__(256) void wconv_kernel(
    const float* __restrict__ src, u16* __restrict__ dst, int R, int C) {
  __shared__ float tile[32][33];
  const int c0 = blockIdx.x * 32, r0 = blockIdx.y * 32;
  const int tx = threadIdx.x, ty = threadIdx.y;
  #pragma unroll
  for (int i = 0; i < 4; i++)
    tile[ty + 8 * i][tx] = src[(long)(r0 + ty + 8 * i) * C + c0 + tx];
  __syncthreads();
  #pragma unroll
  for (int i = 0; i < 4; i++)
    dst[(long)(c0 + ty + 8 * i) * R + r0 + tx] = f2bf(tile[tx][ty + 8 * i]);
}

// ---------------- v_t[(b*16+h)][dh][t] ----------------
__global__ __launch_bounds__(256) void build_vt(
    const u16* __restrict__ qkv, u16* __restrict__ v_t) {
  __shared__ u16 tile[32][33];
  const int z = blockIdx.z, b = z >> 4, h = z & 15;
  const u16* src = qkv + (long)b * 1024 * 3072 + 2048 + h * 64;
  u16* dst = v_t + (long)z * 64 * 1024;
  const int t0 = blockIdx.x * 32, d0 = blockIdx.y * 32;
  const int tx = threadIdx.x, ty = threadIdx.y;
  #pragma unroll
  for (int i = 0; i < 4; i++)
    tile[ty + 8 * i][tx] = src[(long)(t0 + ty + 8 * i) * 3072 + d0 + tx];
  __syncthreads();
  #pragma unroll
  for (int i = 0; i < 4; i++)
    dst[(long)(d0 + ty + 8 * i) * 1024 + t0 + tx] = tile[tx][ty + 8 * i];
}

__global__ __launch_bounds__(256) void bias_concat(
    const float* __restrict__ bq, const float* __restrict__ bk,
    const float* __restrict__ bv, float* __restrict__ out) {
  const int i = blockIdx.x * 256 + threadIdx.x;
  const int l = i / 3072, j = i % 3072;
  float v;
  if (j < 1024)      v = bq[l * 1024 + j];
  else if (j < 2048) v = bk[l * 1024 + j - 1024];
  else               v = bv[l * 1024 + j - 2048];
  out[i] = v;
}

// =====================================================================
// 256x256-tile deep-pipelined GEMM (unchanged from round 3)
// =====================================================================
template <bool OUT_BF16, bool BIAS, bool RELU, bool RESID>
__global__ __launch_bounds__(512) void gemm256_kernel(
    const u16* __restrict__ A, long lda,
    const u16* __restrict__ Bt, long ldb,
    void* __restrict__ Cv, long ldc,
    const float* __restrict__ bias, const float* __restrict__ resid,
    int M, int N, int K, int nTM) {
  __shared__ u16 lds[65536];
  const int nwg = gridDim.x;
  const int qx = nwg >> 3, rx = nwg & 7;
  const int xcd = blockIdx.x & 7, seq = blockIdx.x >> 3;
  const int wg = (xcd < rx ? xcd * (qx + 1) : rx * (qx + 1) + (xcd - rx) * qx) + seq;
  const int tm = wg % nTM, tn = wg / nTM;
  const int rowA0 = tm * 256, rowB0 = tn * 256;

  const int t = threadIdx.x, w = t >> 6, l = t & 63;
  const int lrow = l & 15, kgrp = l >> 4;
  const int wr = w >> 2, wc = w & 3;

  const int srow = t >> 2;
  const int scol = ((t & 3) ^ ((t >> 3) & 3)) * 8;
  const u16* Asrc = A + (long)(rowA0 + srow) * lda + scol;
  const u16* Bsrc = Bt + (long)(rowB0 + srow) * ldb + scol;
  char* ldsB = (char*)lds;
  const int wbase = w * 1024;

  const int fswz = (kgrp ^ ((lrow >> 1) & 3)) * 8;
  const int aoff = (wr * 128 + lrow) * 32 + fswz;
  const int boff = 8192 + (wc * 64 + lrow) * 32 + fswz;

  f32x4 acc[8][4] = {};
  const int NT = K >> 5;

  #pragma unroll
  for (int pt = 0; pt < 3; pt++) {
    const int k0 = pt << 5;
    const int bb = pt * 32768;
    lds_cp16(Asrc + k0,                    ldsB + bb + wbase);
    lds_cp16(Asrc + (long)128 * lda + k0,  ldsB + bb + 8192 + wbase);
    lds_cp16(Bsrc + k0,                    ldsB + bb + 16384 + wbase);
    lds_cp16(Bsrc + (long)128 * ldb + k0,  ldsB + bb + 24576 + wbase);
  }

  for (int tt = 0; tt < NT; tt++) {
    const int rem = NT - 1 - tt;
    if (rem >= 2)      asm volatile("s_waitcnt vmcnt(8)" ::: "memory");
    else if (rem == 1) asm volatile("s_waitcnt vmcnt(4)" ::: "memory");
    else               asm volatile("s_waitcnt vmcnt(0)" ::: "memory");
    __builtin_amdgcn_sched_barrier(0);
    __builtin_amdgcn_s_barrier();

    const u16* buf = lds + (tt & 3) * 16384;
    const int stage = tt + 3 < NT;
    const int k0n = (tt + 3) << 5;
    const int bbn = ((tt + 3) & 3) * 32768;

    bf16x8 aF[4], bF[4];
    #pragma unroll
    for (int m = 0; m < 4; m++) aF[m] = *(const bf16x8*)(buf + aoff + m * 512);
    #pragma unroll
    for (int n = 0; n < 4; n++) bF[n] = *(const bf16x8*)(buf + boff + n * 512);
    if (stage) {
      lds_cp16(Asrc + k0n,                   ldsB + bbn + wbase);
      lds_cp16(Asrc + (long)128 * lda + k0n, ldsB + bbn + 8192 + wbase);
    }
    asm volatile("s_waitcnt lgkmcnt(0)" ::: "memory");
    __builtin_amdgcn_sched_barrier(0);
    __builtin_amdgcn_s_setprio(1);
    #pragma unroll
    for (int m = 0; m < 4; m++)
      #pragma unroll
      for (int n = 0; n < 4; n++)
        acc[m][n] = __builtin_amdgcn_mfma_f32_16x16x32_bf16(aF[m], bF[n], acc[m][n], 0, 0, 0);
    __builtin_amdgcn_s_setprio(0);

    #pragma unroll
    for (int m = 0; m < 4; m++) aF[m] = *(const bf16x8*)(buf + aoff + (m + 4) * 512);
    if (stage) {
      lds_cp16(Bsrc + k0n,                   ldsB + bbn + 16384 + wbase);
      lds_cp16(Bsrc + (long)128 * ldb + k0n, ldsB + bbn + 24576 + wbase);
    }
    asm volatile("s_waitcnt lgkmcnt(0)" ::: "memory");
    __builtin_amdgcn_sched_barrier(0);
    __builtin_amdgcn_s_setprio(1);
    #pragma unroll
    for (int m = 0; m < 4; m++)
      #pragma unroll
      for (int n = 0; n < 4; n++)
        acc[m + 4][n] = __builtin_amdgcn_mfma_f32_16x16x32_bf16(aF[m], bF[n], acc[m + 4][n], 0, 0, 0);
    __builtin_amdgcn_s_setprio(0);
  }

  float bvv[4];
  #pragma unroll
  for (int n = 0; n < 4; n++)
    bvv[n] = BIAS ? bias[rowB0 + wc * 64 + n * 16 + lrow] : 0.0f;
  #pragma unroll
  for (int m = 0; m < 8; m++) {
    const int row = rowA0 + wr * 128 + m * 16 + kgrp * 4;
    #pragma unroll
    for (int n = 0; n < 4; n++) {
      const int col = rowB0 + wc * 64 + n * 16 + lrow;
      #pragma unroll
      for (int j = 0; j < 4; j++) {
        float v = acc[m][n][j] + bvv[n];
        if (RELU) v = fmaxf(v, 0.0f);
        const long off = (long)(row + j) * ldc + col;
        if (RESID) v += resid[off];
        if (OUT_BF16) ((u16*)Cv)[off] = f2bf(v);
        else          ((float*)Cv)[off] = v;
      }
    }
  }
}

// ---------------- generic 128x128 bf16 MFMA GEMM ----------------
template <bool OUT_BF16, bool BIAS, bool RELU, bool RESID>
__global__ __launch_bounds__(256) void gemm_kernel(
    const u16* __restrict__ A, long lda, long sA,
    const u16* __restrict__ Bt, long ldb, long sB,
    void* __restrict__ Cv, long ldc, long sC, int cdiv, long sC2,
    const float* __restrict__ bias, const float* __restrict__ resid,
    int M, int N, int K, int nTM) {
  __shared__ u16 lA[128 * 32];
  __shared__ u16 lB[128 * 32];
  const int nwg = gridDim.x;
  const int qx = nwg >> 3, rx = nwg & 7;
  const int xcd = blockIdx.x & 7, seq = blockIdx.x >> 3;
  const int wg = (xcd < rx ? xcd * (qx + 1) : rx * (qx + 1) + (xcd - rx) * qx) + seq;
  const int tm = wg % nTM, tn = wg / nTM;
  const int batch = blockIdx.y;
  const int t = threadIdx.x, w = t >> 6, l = t & 63;
  A  += (long)batch * sA;
  Bt += (long)batch * sB;
  const int rowA0 = tm * 128, rowB0 = tn * 128;
  const int srow = (w << 4) + (l >> 2);
  const int skel = (l & 3) << 3;
  const int wr = (w >> 1) << 6, wc = (w & 1) << 6;
  const int lrow = l & 15, kgrp = l >> 4;
  f32x4 acc[4][4] = {};

  for (int k0 = 0; k0 < K; k0 += 32) {
    int rB1 = rowB0 + srow;      if (rB1 >= N) rB1 = N - 1;
    int rB2 = rowB0 + 64 + srow; if (rB2 >= N) rB2 = N - 1;
    lds_cp16(A  + (long)(rowA0 + srow) * lda + k0 + skel,      &lA[w * 512]);
    lds_cp16(A  + (long)(rowA0 + 64 + srow) * lda + k0 + skel, &lA[2048 + w * 512]);
    lds_cp16(Bt + (long)rB1 * ldb + k0 + skel,                 &lB[w * 512]);
    lds_cp16(Bt + (long)rB2 * ldb + k0 + skel,                 &lB[2048 + w * 512]);
    __syncthreads();
    bf16x8 af[4], bfr[4];
    #pragma unroll
    for (int m = 0; m < 4; m++)
      af[m] = *(const bf16x8*)&lA[(wr + m * 16 + lrow) * 32 + kgrp * 8];
    #pragma unroll
    for (int n = 0; n < 4; n++)
      bfr[n] = *(const bf16x8*)&lB[(wc + n * 16 + lrow) * 32 + kgrp * 8];
    #pragma unroll
    for (int m = 0; m < 4; m++)
      #pragma unroll
      for (int n = 0; n < 4; n++)
        acc[m][n] = __builtin_amdgcn_mfma_f32_16x16x32_bf16(af[m], bfr[n], acc[m][n], 0, 0, 0);
    __syncthreads();
  }

  const long coff = (long)(batch / cdiv) * sC2 + (long)(batch % cdiv) * sC;
  #pragma unroll
  for (int m = 0; m < 4; m++) {
    #pragma unroll
    for (int n = 0; n < 4; n++) {
      const int col = rowB0 + wc + n * 16 + lrow;
      #pragma unroll
      for (int j = 0; j < 4; j++) {
        const int row = rowA0 + wr + m * 16 + kgrp * 4 + j;
        if (row < M && col < N) {
          float v = acc[m][n][j];
          if (BIAS) v += bias[col];
          if (RELU) v = fmaxf(v, 0.0f);
          const long off = coff + (long)row * ldc + col;
          if (RESID) v += resid[off];
          if (OUT_BF16) ((u16*)Cv)[off] = f2bf(v);
          else          ((float*)Cv)[off] = v;
        }
      }
    }
  }
}

extern "C" void kernel_launch(void* const* d_in, const int* in_sizes, int n_in,
                              void* d_out, int out_size, void* d_ws, size_t ws_size,
                              hipStream_t stream) {
  constexpr int Lc = 4, Tc = 1024, Dc = 1024, Hc = 16, Fc = 4096, DHc = 64;
  const int M = 2 * Tc;
  const int BIG = 1 << 30;

  const int*   idxp       = (const int*)  d_in[0];
  const float* tok_emb    = (const float*)d_in[1];
  const float* pos_emb    = (const float*)d_in[2];
  const float* Wq         = (const float*)d_in[3];
  const float* bq         = (const float*)d_in[4];
  const float* Wk         = (const float*)d_in[5];
  const float* bk         = (const float*)d_in[6];
  const float* Wv         = (const float*)d_in[7];
  const float* bv         = (const float*)d_in[8];
  const float* Wo         = (const float*)d_in[9];
  const float* bo         = (const float*)d_in[10];
  const float* score_gain = (const float*)d_in[11];
  const float* norm1_gain = (const float*)d_in[12];
  const float* norm2_gain = (const float*)d_in[13];
  const float* W1         = (const float*)d_in[14];
  const float* b1         = (const float*)d_in[15];
  const float* W2         = (const float*)d_in[16];
  const float* b2         = (const float*)d_in[17];
  const float* final_gain = (const float*)d_in[18];
  const float* Wlm        = (const float*)d_in[19];
  const float* blm        = (const float*)d_in[20];

  char* p = (char*)d_ws;
  auto alloc = [&](size_t n) { char* r = p; p += (n + 255) & ~(size_t)255; return r; };
  u16*  wqkv_t = (u16*) alloc((size_t)Lc * 3072 * 1024 * 2);
  u16*  wo_t   = (u16*) alloc((size_t)Lc * 1024 * 1024 * 2);
  u16*  w1_t   = (u16*) alloc((size_t)Lc * 4096 * 1024 * 2);
  u16*  w2_t   = (u16*) alloc((size_t)Lc * 1024 * 4096 * 2);
  u16*  wlm_t  = (u16*) alloc((size_t)32000 * 1024 * 2);
  float* bqkv  = (float*)alloc((size_t)Lc * 3072 * 4);
  float* x     = (float*)alloc((size_t)M * 1024 * 4);
  u16*  hbuf   = (u16*) alloc((size_t)M * 1024 * 2);
  u16*  qkv    = (u16*) alloc((size_t)M * 3072 * 2);
  u16*  v_t    = (u16*) alloc((size_t)2 * Hc * DHc * Tc * 2);
  u16*  obuf   = (u16*) alloc((size_t)M * 1024 * 2);
  u16*  ffh    = (u16*) alloc((size_t)M * 4096 * 2);

  const dim3 tb(32, 8);
  for (int l = 0; l < Lc; l++) {
    wconv_kernel<<<dim3(32, 32), tb, 0, stream>>>(Wq + (size_t)l * Dc * Dc, wqkv_t + ((size_t)l * 3072 + 0) * 1024, 1024, 1024);
    wconv_kernel<<<dim3(32, 32), tb, 0, stream>>>(Wk + (size_t)l * Dc * Dc, wqkv_t + ((size_t)l * 3072 + 1024) * 1024, 1024, 1024);
    wconv_kernel<<<dim3(32, 32), tb, 0, stream>>>(Wv + (size_t)l * Dc * Dc, wqkv_t + ((size_t)l * 3072 + 2048) * 1024, 1024, 1024);
    wconv_kernel<<<dim3(32, 32), tb, 0, stream>>>(Wo + (size_t)l * Dc * Dc, wo_t + (size_t)l * 1024 * 1024, 1024, 1024);
    wconv_kernel<<<dim3(128, 32), tb, 0, stream>>>(W1 + (size_t)l * Dc * Fc, w1_t + (size_t)l * Fc * Dc, 1024, 4096);
    wconv_kernel<<<dim3(32, 128), tb, 0, stream>>>(W2 + (size_t)l * Fc * Dc, w2_t + (size_t)l * Dc * Fc, 4096, 1024);
  }
  wconv_kernel<<<dim3(1000, 32), tb, 0, stream>>>(Wlm, wlm_t, 1024, 32000);
  bias_concat<<<48, 256, 0, stream>>>(bq, bk, bv, bqkv);

  embed_kernel<<<M, 256, 0, stream>>>(idxp, tok_emb, pos_emb, x);

  for (int l = 0; l < Lc; l++) {
    anorm_kernel<<<M, 256, 0, stream>>>(x, norm1_gain + (size_t)l * Dc, hbuf);
    gemm_kernel<true, true, false, false><<<dim3(16 * 24, 1), 256, 0, stream>>>(
        hbuf, 1024, 0, wqkv_t + (size_t)l * 3072 * 1024, 1024, 0,
        qkv, 3072, 0, BIG, 0, bqkv + (size_t)l * 3072, nullptr, M, 3072, 1024, 16);
    build_vt<<<dim3(32, 2, 32), tb, 0, stream>>>(qkv, v_t);

    // fused scores + rational softmax + PV -> obuf
    attn_fused_kernel<<<dim3(32, 16, 2), 256, 0, stream>>>(qkv, v_t, obuf, score_gain, l);

    gemm_kernel<false, true, false, true><<<dim3(16 * 8, 1), 256, 0, stream>>>(
        obuf, 1024, 0, wo_t + (size_t)l * 1024 * 1024, 1024, 0,
        x, 1024, 0, BIG, 0, bo + (size_t)l * 1024, x, M, 1024, 1024, 16);
    anorm_kernel<<<M, 256, 0, stream>>>(x, norm2_gain + (size_t)l * Dc, hbuf);
    gemm256_kernel<true, true, true, false><<<dim3(128), 512, 0, stream>>>(
        hbuf, 1024, w1_t + (size_t)l * Fc * Dc, 1024,
        ffh, 4096, b1 + (size_t)l * Fc, nullptr, M, 4096, 1024, 8);
    gemm_kernel<false, true, false, true><<<dim3(16 * 8, 1), 256, 0, stream>>>(
        ffh, 4096, 0, w2_t + (size_t)l * Dc * Fc, 4096, 0,
        x, 1024, 0, BIG, 0, b2 + (size_t)l * Dc, x, M, 1024, 4096, 16);
  }

  anorm_kernel<<<M, 256, 0, stream>>>(x, final_gain, hbuf);
  gemm256_kernel<false, true, false, false><<<dim3(1000), 512, 0, stream>>>(
      hbuf, 1024, wlm_t, 1024,
      d_out, 32000, blm, nullptr, M, 32000, 1024, 8);
}

// Round 5
// 1412.637 us; speedup vs baseline: 1.4006x; 1.1114x over previous
//
#include <hip/hip_runtime.h>

typedef unsigned short u16;
typedef __bf16 bf16x8 __attribute__((ext_vector_type(8)));
typedef float f32x4 __attribute__((ext_vector_type(4)));
typedef unsigned int u32;

#define EPSF 1e-6f

__device__ __forceinline__ u16 f2bf(float f) {
  union { float f; unsigned u; } un; un.f = f;
  unsigned r = un.u + 0x7FFFu + ((un.u >> 16) & 1u);
  return (u16)(r >> 16);
}
__device__ __forceinline__ float bf2f(u16 v) {
  union { u32 u; float f; } un; un.u = ((u32)v) << 16; return un.f;
}

__device__ __forceinline__ float block_sum(float v) {
  #pragma unroll
  for (int off = 32; off > 0; off >>= 1) v += __shfl_xor(v, off, 64);
  __shared__ float ws[4];
  const int w = threadIdx.x >> 6;
  __syncthreads();
  if ((threadIdx.x & 63) == 0) ws[w] = v;
  __syncthreads();
  return ws[0] + ws[1] + ws[2] + ws[3];
}

// async global->LDS, 16B per lane. LDS dest must be wave-uniform base; HW adds lane*16.
__device__ __forceinline__ void lds_cp16(const void* g, void* l) {
  __builtin_amdgcn_global_load_lds(
      (__attribute__((address_space(1))) void*)g,
      (__attribute__((address_space(3))) void*)l, 16, 0, 0);
}

// ---------------- embedding ----------------
__global__ __launch_bounds__(256) void embed_kernel(
    const int* __restrict__ idx, const float* __restrict__ tok,
    const float* __restrict__ pos, float* __restrict__ x) {
  const int row = blockIdx.x;
  const int tpos = row & 1023;
  const int token = idx[row];
  const int d = threadIdx.x * 4;
  const float4 a = *(const float4*)(tok + (long)token * 1024 + d);
  const float4 b = *(const float4*)(pos + (long)tpos * 1024 + d);
  float4 o; o.x = a.x + b.x; o.y = a.y + b.y; o.z = a.z + b.z; o.w = a.w + b.w;
  *(float4*)(x + (long)row * 1024 + d) = o;
}

// ---------------- anorm ----------------
__global__ __launch_bounds__(256) void anorm_kernel(
    const float* __restrict__ x, const float* __restrict__ gain,
    u16* __restrict__ h) {
  const int row = blockIdx.x;
  const int tid = threadIdx.x;
  const float4 v = *(const float4*)(x + (long)row * 1024 + tid * 4);
  float s = fabsf(v.x) + fabsf(v.y) + fabsf(v.z) + fabsf(v.w);
  s = block_sum(s);
  const float scale = 1.0f / (s * (1.0f / 1024.0f) + EPSF);
  const float4 g = *(const float4*)(gain + tid * 4);
  ushort4 o;
  o.x = f2bf(v.x * g.x * scale);
  o.y = f2bf(v.y * g.y * scale);
  o.z = f2bf(v.z * g.z * scale);
  o.w = f2bf(v.w * g.w * scale);
  *(ushort4*)(h + (long)row * 1024 + tid * 4) = o;
}

// =====================================================================
// Fused attention v2: QK^T + rational softmax + PV. One block per
// (b, h, 32 q-rows), 4 waves. K/V/Q fragments loaded DIRECTLY from
// global (L2-resident: 128KB K + 128KB V per head, shared by 32 blocks)
// with 2-deep register double-buffering. Only the 64KB S panel lives in
// LDS (XOR-swizzled). Exactly 2 block-wide barriers total.
// =====================================================================
__global__ __launch_bounds__(256) void attn_fused_kernel(
    const u16* __restrict__ qkv,      // [b][t][3072] bf16 (Q,K planes)
    const u16* __restrict__ v_t,      // [(b*16+h)][64][1024] bf16
    u16* __restrict__ obuf,           // [b*1024+t][1024] bf16
    const float* __restrict__ score_gain, int l) {
  __shared__ u16 Sb[32 * 1024];       // 64 KB score/P panel (swizzled chunks)
  const int qt = blockIdx.x, h = blockIdx.y, b = blockIdx.z;
  const int tid = threadIdx.x, w = tid >> 6, l64 = tid & 63;
  const int q0 = qt * 32;
  const u16* Qg = qkv + (size_t)b * (1024 * 3072) + h * 64;
  const u16* Kg = Qg + 1024;
  const u16* Vt = v_t + (size_t)(b * 16 + h) * (64 * 1024);

  const int lrow = l64 & 15, kgrp = l64 >> 4;
  const int qstripe = (w & 1) << 4;   // q-row stripe 0/16
  const int npair = (w >> 1) << 1;    // col-frag base 0/2

  // S element index (u16 units): chunk-of-8 XOR row&7
  auto sidx = [](int row, int t) {
    return (row << 10) + ((((t >> 3) ^ (row & 7)) << 3) | (t & 7));
  };

  // ---- Q fragments direct from global ----
  bf16x8 qf[2];
  {
    const u16* qp = Qg + (size_t)(q0 + qstripe + lrow) * 3072 + (kgrp << 3);
    qf[0] = *(const bf16x8*)(qp);
    qf[1] = *(const bf16x8*)(qp + 32);
  }

  // ---- QK^T: 16 tiles of 64 cols, reg-double-buffered K frags ----
  const u16* Kbase = Kg + (size_t)((npair << 4) + lrow) * 3072 + (kgrp << 3);
#define LOADK(dst, ct) do {                                   \
    const u16* p_ = Kbase + (size_t)(ct) * 196608;            \
    dst[0][0] = *(const bf16x8*)(p_);                         \
    dst[0][1] = *(const bf16x8*)(p_ + 32);                    \
    dst[1][0] = *(const bf16x8*)(p_ + 49152);                 \
    dst[1][1] = *(const bf16x8*)(p_ + 49152 + 32); } while (0)

  auto qk_step = [&](const bf16x8 (&kf)[2][2], int ct) {
    f32x4 a0 = {0.f, 0.f, 0.f, 0.f}, a1 = {0.f, 0.f, 0.f, 0.f};
    a0 = __builtin_amdgcn_mfma_f32_16x16x32_bf16(qf[0], kf[0][0], a0, 0, 0, 0);
    a0 = __builtin_amdgcn_mfma_f32_16x16x32_bf16(qf[1], kf[0][1], a0, 0, 0, 0);
    a1 = __builtin_amdgcn_mfma_f32_16x16x32_bf16(qf[0], kf[1][0], a1, 0, 0, 0);
    a1 = __builtin_amdgcn_mfma_f32_16x16x32_bf16(qf[1], kf[1][1], a1, 0, 0, 0);
    const int colbase = (ct << 6) + (npair << 4) + lrow;
    #pragma unroll
    for (int j = 0; j < 4; j++) {
      const int row = qstripe + (kgrp << 2) + j;
      Sb[sidx(row, colbase)]      = f2bf(a0[j]);
      Sb[sidx(row, colbase + 16)] = f2bf(a1[j]);
    }
  };

  {
    bf16x8 kA[2][2], kB[2][2];
    LOADK(kA, 0);
    #pragma unroll
    for (int ct = 0; ct < 16; ct += 2) {
      LOADK(kB, ct + 1);
      qk_step(kA, ct);
      if (ct + 2 < 16) LOADK(kA, ct + 2);
      qk_step(kB, ct + 1);
    }
  }
  __syncthreads();

  // ---- per-row stats + rational softmax (wave w owns rows 8w..8w+7) ----
  const float gain = score_gain[l];
  #pragma unroll 1
  for (int r = 0; r < 8; r++) {
    const int row = (w << 3) + r;
    const int qglob = q0 + row;
    float sreg[16], p[16];
    float ssum = 0.f;
    #pragma unroll
    for (int i = 0; i < 8; i++) {
      const int t = (l64 << 1) + (i << 7);
      const u32 v = *(const u32*)&Sb[sidx(row, t)];
      sreg[2 * i]     = bf2f((u16)(v & 0xffff));
      sreg[2 * i + 1] = bf2f((u16)(v >> 16));
      ssum += sreg[2 * i] + sreg[2 * i + 1];
    }
    #pragma unroll
    for (int off = 32; off; off >>= 1) ssum += __shfl_xor(ssum, off, 64);
    const float mean = ssum * (1.0f / 1024.0f);
    float asum = 0.f;
    #pragma unroll
    for (int i = 0; i < 16; i++) asum += fabsf(sreg[i] - mean);
    #pragma unroll
    for (int off = 32; off; off >>= 1) asum += __shfl_xor(asum, off, 64);
    const float gs = gain / (asum * (1.0f / 1024.0f) + EPSF);
    float ps = 0.f;
    #pragma unroll
    for (int i = 0; i < 8; i++) {
      #pragma unroll
      for (int u = 0; u < 2; u++) {
        const int t = (l64 << 1) + (i << 7) + u;
        float sv = (sreg[2 * i + u] - mean) * gs;
        if (t > qglob) sv = -1000.0f;
        const float rr = sv / (fabsf(sv) + 1.0f);
        const float a1 = (rr + 1.0f) * 0.5f;
        const float a2 = a1 * a1;
        p[2 * i + u] = a2 * a2;
        ps += p[2 * i + u];
      }
    }
    #pragma unroll
    for (int off = 32; off; off >>= 1) ps += __shfl_xor(ps, off, 64);
    const float inv = 1.0f / (ps + EPSF);
    #pragma unroll
    for (int i = 0; i < 8; i++) {
      const int t = (l64 << 1) + (i << 7);
      const u32 packed = (u32)f2bf(p[2 * i] * inv) | ((u32)f2bf(p[2 * i + 1] * inv) << 16);
      *(u32*)&Sb[sidx(row, t)] = packed;
    }
  }
  __syncthreads();

  // ---- PV: O[32][64] = P @ V, reg-double-buffered V frags + LDS P frags ----
  const u16* Vbase = Vt + (size_t)((npair << 4) + lrow) * 1024 + (kgrp << 3);
#define LOADV(dst, vt) do {                                   \
    const u16* p_ = Vbase + ((vt) << 6);                      \
    dst[0][0] = *(const bf16x8*)(p_);                         \
    dst[0][1] = *(const bf16x8*)(p_ + 32);                    \
    dst[1][0] = *(const bf16x8*)(p_ + 16384);                 \
    dst[1][1] = *(const bf16x8*)(p_ + 16384 + 32); } while (0)
#define LOADP(dst, vt) do {                                   \
    const int r_ = qstripe + lrow;                            \
    const int t0_ = ((vt) << 6) + (kgrp << 3);                \
    dst[0] = *(const bf16x8*)&Sb[(r_ << 10) + ((((t0_ >> 3) ^ (r_ & 7)) << 3))];          \
    dst[1] = *(const bf16x8*)&Sb[(r_ << 10) + (((((t0_ + 32) >> 3) ^ (r_ & 7)) << 3))]; } while (0)

  f32x4 aco[2] = {};
  auto pv_step = [&](const bf16x8 (&pf)[2], const bf16x8 (&vf)[2][2]) {
    aco[0] = __builtin_amdgcn_mfma_f32_16x16x32_bf16(pf[0], vf[0][0], aco[0], 0, 0, 0);
    aco[0] = __builtin_amdgcn_mfma_f32_16x16x32_bf16(pf[1], vf[0][1], aco[0], 0, 0, 0);
    aco[1] = __builtin_amdgcn_mfma_f32_16x16x32_bf16(pf[0], vf[1][0], aco[1], 0, 0, 0);
    aco[1] = __builtin_amdgcn_mfma_f32_16x16x32_bf16(pf[1], vf[1][1], aco[1], 0, 0, 0);
  };
  {
    bf16x8 vA[2][2], vB[2][2], pA[2], pB[2];
    LOADV(vA, 0); LOADP(pA, 0);
    #pragma unroll
    for (int vt = 0; vt < 16; vt += 2) {
      LOADV(vB, vt + 1); LOADP(pB, vt + 1);
      pv_step(pA, vA);
      if (vt + 2 < 16) { LOADV(vA, vt + 2); LOADP(pA, vt + 2); }
      pv_step(pB, vB);
    }
  }

  // ---- epilogue: O -> obuf[b*1024+q][h*64+dh] ----
  u16* Ob = obuf + ((size_t)((b << 10) + q0 + qstripe + (kgrp << 2)) << 10) + (h << 6);
  #pragma unroll
  for (int nf = 0; nf < 2; nf++) {
    const int dh = ((npair + nf) << 4) + lrow;
    #pragma unroll
    for (int j = 0; j < 4; j++)
      Ob[(size_t)j << 10 | dh] = f2bf(aco[nf][j]);
  }
#undef LOADK
#undef LOADV
#undef LOADP
}

// ---------------- all weight conversions in ONE dispatch ----------------
// dst[c][r] = bf16(src[r][c]) per 32x32 tile; block id decodes which matrix.
__global__ __launch_bounds__(256) void wconv_all(
    const float* __restrict__ Wq, const float* __restrict__ Wk,
    const float* __restrict__ Wv, const float* __restrict__ Wo,
    const float* __restrict__ W1, const float* __restrict__ W2,
    const float* __restrict__ Wlm,
    u16* __restrict__ wqkv_t, u16* __restrict__ wo_t,
    u16* __restrict__ w1_t, u16* __restrict__ w2_t, u16* __restrict__ wlm_t) {
  __shared__ float tile[32][33];
  const int bid = blockIdx.x;
  const float* src; u16* dst; int R, C, c0, r0;
  if (bid < 16384) {            // Wq/Wk/Wv/Wo: [1024][1024] each, 1024 tiles
    const int l = bid >> 12, m = (bid >> 10) & 3, t = bid & 1023;
    if (m == 0)      src = Wq + (size_t)l * 1048576;
    else if (m == 1) src = Wk + (size_t)l * 1048576;
    else if (m == 2) src = Wv + (size_t)l * 1048576;
    else             src = Wo + (size_t)l * 1048576;
    dst = (m < 3) ? wqkv_t + ((size_t)l * 3072 + m * 1024) * 1024
                  : wo_t + (size_t)l * 1048576;
    R = 1024; C = 1024; c0 = (t & 31) << 5; r0 = (t >> 5) << 5;
  } else if (bid < 32768) {     // W1: [1024][4096]
    const int i = bid - 16384, l = i >> 12, t = i & 4095;
    src = W1 + (size_t)l * 4194304; dst = w1_t + (size_t)l * 4194304;
    R = 1024; C = 4096; c0 = (t & 127) << 5; r0 = (t >> 7) << 5;
  } else if (bid < 49152) {     // W2: [4096][1024]
    const int i = bid - 32768, l = i >> 12, t = i & 4095;
    src = W2 + (size_t)l * 4194304; dst = w2_t + (size_t)l * 4194304;
    R = 4096; C = 1024; c0 = (t & 31) << 5; r0 = (t >> 5) << 5;
  } else {                      // Wlm: [1024][32000]
    const int i = bid - 49152;
    src = Wlm; dst = wlm_t;
    R = 1024; C = 32000; c0 = (i % 1000) << 5; r0 = (i / 1000) << 5;
  }
  const int tx = threadIdx.x, ty = threadIdx.y;
  #pragma unroll
  for (int i = 0; i < 4; i++)
    tile[ty + 8 * i][tx] = src[(long)(r0 + ty + 8 * i) * C + c0 + tx];
  __syncthreads();
  #pragma unroll
  for (int i = 0; i < 4; i++)
    dst[(long)(c0 + ty + 8 * i) * R + r0 + tx] = f2bf(tile[tx][ty + 8 * i]);
}

__global__ __launch_bounds__(256) void bias_concat(
    const float* __restrict__ bq, const float* __restrict__ bk,
    const float* __restrict__ bv, float* __restrict__ out) {
  const int i = blockIdx.x * 256 + threadIdx.x;
  const int l = i / 3072, j = i % 3072;
  float v;
  if (j < 1024)      v = bq[l * 1024 + j];
  else if (j < 2048) v = bk[l * 1024 + j - 1024];
  else               v = bv[l * 1024 + j - 2048];
  out[i] = v;
}

// ---------------- FFN2 split-K reduce: x += p0 + p1 + b2 ----------------
__global__ __launch_bounds__(256) void ffn2_reduce(
    const float* __restrict__ part, const float* __restrict__ b2,
    float* __restrict__ x) {
  const int row = blockIdx.x, c = threadIdx.x * 4;
  const float4 p0 = *(const float4*)(part + (size_t)row * 1024 + c);
  const float4 p1 = *(const float4*)(part + (size_t)(row + 2048) * 1024 + c);
  const float4 bb = *(const float4*)(b2 + c);
  float4 xv = *(float4*)(x + (size_t)row * 1024 + c);
  xv.x += p0.x + p1.x + bb.x;
  xv.y += p0.y + p1.y + bb.y;
  xv.z += p0.z + p1.z + bb.z;
  xv.w += p0.w + p1.w + bb.w;
  *(float4*)(x + (size_t)row * 1024 + c) = xv;
}

// =====================================================================
// 256x256-tile deep-pipelined GEMM (unchanged)
// =====================================================================
template <bool OUT_BF16, bool BIAS, bool RELU, bool RESID>
__global__ __launch_bounds__(512) void gemm256_kernel(
    const u16* __restrict__ A, long lda,
    const u16* __restrict__ Bt, long ldb,
    void* __restrict__ Cv, long ldc,
    const float* __restrict__ bias, const float* __restrict__ resid,
    int M, int N, int K, int nTM) {
  __shared__ u16 lds[65536];
  const int nwg = gridDim.x;
  const int qx = nwg >> 3, rx = nwg & 7;
  const int xcd = blockIdx.x & 7, seq = blockIdx.x >> 3;
  const int wg = (xcd < rx ? xcd * (qx + 1) : rx * (qx + 1) + (xcd - rx) * qx) + seq;
  const int tm = wg % nTM, tn = wg / nTM;
  const int rowA0 = tm * 256, rowB0 = tn * 256;

  const int t = threadIdx.x, w = t >> 6, l = t & 63;
  const int lrow = l & 15, kgrp = l >> 4;
  const int wr = w >> 2, wc = w & 3;

  const int srow = t >> 2;
  const int scol = ((t & 3) ^ ((t >> 3) & 3)) * 8;
  const u16* Asrc = A + (long)(rowA0 + srow) * lda + scol;
  const u16* Bsrc = Bt + (long)(rowB0 + srow) * ldb + scol;
  char* ldsB = (char*)lds;
  const int wbase = w * 1024;

  const int fswz = (kgrp ^ ((lrow >> 1) & 3)) * 8;
  const int aoff = (wr * 128 + lrow) * 32 + fswz;
  const int boff = 8192 + (wc * 64 + lrow) * 32 + fswz;

  f32x4 acc[8][4] = {};
  const int NT = K >> 5;

  #pragma unroll
  for (int pt = 0; pt < 3; pt++) {
    const int k0 = pt << 5;
    const int bb = pt * 32768;
    lds_cp16(Asrc + k0,                    ldsB + bb + wbase);
    lds_cp16(Asrc + (long)128 * lda + k0,  ldsB + bb + 8192 + wbase);
    lds_cp16(Bsrc + k0,                    ldsB + bb + 16384 + wbase);
    lds_cp16(Bsrc + (long)128 * ldb + k0,  ldsB + bb + 24576 + wbase);
  }

  for (int tt = 0; tt < NT; tt++) {
    const int rem = NT - 1 - tt;
    if (rem >= 2)      asm volatile("s_waitcnt vmcnt(8)" ::: "memory");
    else if (rem == 1) asm volatile("s_waitcnt vmcnt(4)" ::: "memory");
    else               asm volatile("s_waitcnt vmcnt(0)" ::: "memory");
    __builtin_amdgcn_sched_barrier(0);
    __builtin_amdgcn_s_barrier();

    const u16* buf = lds + (tt & 3) * 16384;
    const int stage = tt + 3 < NT;
    const int k0n = (tt + 3) << 5;
    const int bbn = ((tt + 3) & 3) * 32768;

    bf16x8 aF[4], bF[4];
    #pragma unroll
    for (int m = 0; m < 4; m++) aF[m] = *(const bf16x8*)(buf + aoff + m * 512);
    #pragma unroll
    for (int n = 0; n < 4; n++) bF[n] = *(const bf16x8*)(buf + boff + n * 512);
    if (stage) {
      lds_cp16(Asrc + k0n,                   ldsB + bbn + wbase);
      lds_cp16(Asrc + (long)128 * lda + k0n, ldsB + bbn + 8192 + wbase);
    }
    asm volatile("s_waitcnt lgkmcnt(0)" ::: "memory");
    __builtin_amdgcn_sched_barrier(0);
    __builtin_amdgcn_s_setprio(1);
    #pragma unroll
    for (int m = 0; m < 4; m++)
      #pragma unroll
      for (int n = 0; n < 4; n++)
        acc[m][n] = __builtin_amdgcn_mfma_f32_16x16x32_bf16(aF[m], bF[n], acc[m][n], 0, 0, 0);
    __builtin_amdgcn_s_setprio(0);

    #pragma unroll
    for (int m = 0; m < 4; m++) aF[m] = *(const bf16x8*)(buf + aoff + (m + 4) * 512);
    if (stage) {
      lds_cp16(Bsrc + k0n,                   ldsB + bbn + 16384 + wbase);
      lds_cp16(Bsrc + (long)128 * ldb + k0n, ldsB + bbn + 24576 + wbase);
    }
    asm volatile("s_waitcnt lgkmcnt(0)" ::: "memory");
    __builtin_amdgcn_sched_barrier(0);
    __builtin_amdgcn_s_setprio(1);
    #pragma unroll
    for (int m = 0; m < 4; m++)
      #pragma unroll
      for (int n = 0; n < 4; n++)
        acc[m + 4][n] = __builtin_amdgcn_mfma_f32_16x16x32_bf16(aF[m], bF[n], acc[m + 4][n], 0, 0, 0);
    __builtin_amdgcn_s_setprio(0);
  }

  float bvv[4];
  #pragma unroll
  for (int n = 0; n < 4; n++)
    bvv[n] = BIAS ? bias[rowB0 + wc * 64 + n * 16 + lrow] : 0.0f;
  #pragma unroll
  for (int m = 0; m < 8; m++) {
    const int row = rowA0 + wr * 128 + m * 16 + kgrp * 4;
    #pragma unroll
    for (int n = 0; n < 4; n++) {
      const int col = rowB0 + wc * 64 + n * 16 + lrow;
      #pragma unroll
      for (int j = 0; j < 4; j++) {
        float v = acc[m][n][j] + bvv[n];
        if (RELU) v = fmaxf(v, 0.0f);
        const long off = (long)(row + j) * ldc + col;
        if (RESID) v += resid[off];
        if (OUT_BF16) ((u16*)Cv)[off] = f2bf(v);
        else          ((float*)Cv)[off] = v;
      }
    }
  }
}

// ---------------- generic 128x128 bf16 MFMA GEMM ----------------
// VTOUT: columns >=2048 are the V-projection; write them transposed into
// v_t[(b*16+h)][dh][t] instead of the C matrix.
template <bool OUT_BF16, bool BIAS, bool RELU, bool RESID, bool VTOUT>
__global__ __launch_bounds__(256) void gemm_kernel(
    const u16* __restrict__ A, long lda, long sA,
    const u16* __restrict__ Bt, long ldb, long sB,
    void* __restrict__ Cv, long ldc, long sC, int cdiv, long sC2,
    const float* __restrict__ bias, const float* __restrict__ resid,
    u16* __restrict__ vtout,
    int M, int N, int K, int nTM) {
  __shared__ u16 lA[128 * 32];
  __shared__ u16 lB[128 * 32];
  const int nwg = gridDim.x;
  const int qx = nwg >> 3, rx = nwg & 7;
  const int xcd = blockIdx.x & 7, seq = blockIdx.x >> 3;
  const int wg = (xcd < rx ? xcd * (qx + 1) : rx * (qx + 1) + (xcd - rx) * qx) + seq;
  const int tm = wg % nTM, tn = wg / nTM;
  const int batch = blockIdx.y;
  const int t = threadIdx.x, w = t >> 6, l = t & 63;
  A  += (long)batch * sA;
  Bt += (long)batch * sB;
  const int rowA0 = tm * 128, rowB0 = tn * 128;
  const int srow = (w << 4) + (l >> 2);
  const int skel = (l & 3) << 3;
  const int wr = (w >> 1) << 6, wc = (w & 1) << 6;
  const int lrow = l & 15, kgrp = l >> 4;
  f32x4 acc[4][4] = {};

  for (int k0 = 0; k0 < K; k0 += 32) {
    int rB1 = rowB0 + srow;      if (rB1 >= N) rB1 = N - 1;
    int rB2 = rowB0 + 64 + srow; if (rB2 >= N) rB2 = N - 1;
    lds_cp16(A  + (long)(rowA0 + srow) * lda + k0 + skel,      &lA[w * 512]);
    lds_cp16(A  + (long)(rowA0 + 64 + srow) * lda + k0 + skel, &lA[2048 + w * 512]);
    lds_cp16(Bt + (long)rB1 * ldb + k0 + skel,                 &lB[w * 512]);
    lds_cp16(Bt + (long)rB2 * ldb + k0 + skel,                 &lB[2048 + w * 512]);
    __syncthreads();
    bf16x8 af[4], bfr[4];
    #pragma unroll
    for (int m = 0; m < 4; m++)
      af[m] = *(const bf16x8*)&lA[(wr + m * 16 + lrow) * 32 + kgrp * 8];
    #pragma unroll
    for (int n = 0; n < 4; n++)
      bfr[n] = *(const bf16x8*)&lB[(wc + n * 16 + lrow) * 32 + kgrp * 8];
    #pragma unroll
    for (int m = 0; m < 4; m++)
      #pragma unroll
      for (int n = 0; n < 4; n++)
        acc[m][n] = __builtin_amdgcn_mfma_f32_16x16x32_bf16(af[m], bfr[n], acc[m][n], 0, 0, 0);
    __syncthreads();
  }

  const long coff = (long)(batch / cdiv) * sC2 + (long)(batch % cdiv) * sC;
  #pragma unroll
  for (int m = 0; m < 4; m++) {
    #pragma unroll
    for (int n = 0; n < 4; n++) {
      const int col = rowB0 + wc + n * 16 + lrow;
      #pragma unroll
      for (int j = 0; j < 4; j++) {
        const int row = rowA0 + wr + m * 16 + kgrp * 4 + j;
        if (row < M && col < N) {
          float v = acc[m][n][j];
          if (BIAS) v += bias[col];
          if (RELU) v = fmaxf(v, 0.0f);
          if (VTOUT && col >= 2048) {
            const int bb = row >> 10, tt = row & 1023;
            const int hh = (col - 2048) >> 6, dh = col & 63;
            vtout[((size_t)((bb << 4) + hh) << 16) + ((size_t)dh << 10) + tt] = f2bf(v);
          } else {
            const long off = coff + (long)row * ldc + col;
            float v2 = v;
            if (RESID) v2 += resid[off];
            if (OUT_BF16) ((u16*)Cv)[off] = f2bf(v2);
            else          ((float*)Cv)[off] = v2;
          }
        }
      }
    }
  }
}

extern "C" void kernel_launch(void* const* d_in, const int* in_sizes, int n_in,
                              void* d_out, int out_size, void* d_ws, size_t ws_size,
                              hipStream_t stream) {
  constexpr int Lc = 4, Tc = 1024, Dc = 1024, Hc = 16, Fc = 4096, DHc = 64;
  const int M = 2 * Tc;
  const int BIG = 1 << 30;

  const int*   idxp       = (const int*)  d_in[0];
  const float* tok_emb    = (const float*)d_in[1];
  const float* pos_emb    = (const float*)d_in[2];
  const float* Wq         = (const float*)d_in[3];
  const float* bq         = (const float*)d_in[4];
  const float* Wk         = (const float*)d_in[5];
  const float* bk         = (const float*)d_in[6];
  const float* Wv         = (const float*)d_in[7];
  const float* bv         = (const float*)d_in[8];
  const float* Wo         = (const float*)d_in[9];
  const float* bo         = (const float*)d_in[10];
  const float* score_gain = (const float*)d_in[11];
  const float* norm1_gain = (const float*)d_in[12];
  const float* norm2_gain = (const float*)d_in[13];
  const float* W1         = (const float*)d_in[14];
  const float* b1         = (const float*)d_in[15];
  const float* W2         = (const float*)d_in[16];
  const float* b2         = (const float*)d_in[17];
  const float* final_gain = (const float*)d_in[18];
  const float* Wlm        = (const float*)d_in[19];
  const float* blm        = (const float*)d_in[20];

  char* p = (char*)d_ws;
  auto alloc = [&](size_t n) { char* r = p; p += (n + 255) & ~(size_t)255; return r; };
  u16*  wqkv_t = (u16*) alloc((size_t)Lc * 3072 * 1024 * 2);
  u16*  wo_t   = (u16*) alloc((size_t)Lc * 1024 * 1024 * 2);
  u16*  w1_t   = (u16*) alloc((size_t)Lc * 4096 * 1024 * 2);
  u16*  w2_t   = (u16*) alloc((size_t)Lc * 1024 * 4096 * 2);
  u16*  wlm_t  = (u16*) alloc((size_t)32000 * 1024 * 2);
  float* bqkv  = (float*)alloc((size_t)Lc * 3072 * 4);
  float* x     = (float*)alloc((size_t)M * 1024 * 4);
  u16*  hbuf   = (u16*) alloc((size_t)M * 1024 * 2);
  u16*  qkv    = (u16*) alloc((size_t)M * 3072 * 2);
  u16*  v_t    = (u16*) alloc((size_t)2 * Hc * DHc * Tc * 2);
  u16*  obuf   = (u16*) alloc((size_t)M * 1024 * 2);
  u16*  ffh    = (u16*) alloc((size_t)M * 4096 * 2);
  float* fpart = (float*)alloc((size_t)2 * M * 1024 * 4);

  const dim3 tb(32, 8);
  wconv_all<<<81152, tb, 0, stream>>>(Wq, Wk, Wv, Wo, W1, W2, Wlm,
                                      wqkv_t, wo_t, w1_t, w2_t, wlm_t);
  bias_concat<<<48, 256, 0, stream>>>(bq, bk, bv, bqkv);
  embed_kernel<<<M, 256, 0, stream>>>(idxp, tok_emb, pos_emb, x);

  for (int l = 0; l < Lc; l++) {
    anorm_kernel<<<M, 256, 0, stream>>>(x, norm1_gain + (size_t)l * Dc, hbuf);
    // QKV gemm; V columns go transposed straight into v_t
    gemm_kernel<true, true, false, false, true><<<dim3(16 * 24, 1), 256, 0, stream>>>(
        hbuf, 1024, 0, wqkv_t + (size_t)l * 3072 * 1024, 1024, 0,
        qkv, 3072, 0, BIG, 0, bqkv + (size_t)l * 3072, nullptr, v_t, M, 3072, 1024, 16);

    // fused attention v2 (barrier-light, reg-frag K/V)
    attn_fused_kernel<<<dim3(32, 16, 2), 256, 0, stream>>>(qkv, v_t, obuf, score_gain, l);

    gemm_kernel<false, true, false, true, false><<<dim3(16 * 8, 1), 256, 0, stream>>>(
        obuf, 1024, 0, wo_t + (size_t)l * 1024 * 1024, 1024, 0,
        x, 1024, 0, BIG, 0, bo + (size_t)l * 1024, x, nullptr, M, 1024, 1024, 16);
    anorm_kernel<<<M, 256, 0, stream>>>(x, norm2_gain + (size_t)l * Dc, hbuf);
    gemm256_kernel<true, true, true, false><<<dim3(128), 512, 0, stream>>>(
        hbuf, 1024, w1_t + (size_t)l * Fc * Dc, 1024,
        ffh, 4096, b1 + (size_t)l * Fc, nullptr, M, 4096, 1024, 8);
    // FFN2 split-K=2: grid (128,2), K=2048 each, f32 partials
    gemm_kernel<false, false, false, false, false><<<dim3(128, 2), 256, 0, stream>>>(
        ffh, 4096, 2048, w2_t + (size_t)l * Dc * Fc, 4096, 2048,
        fpart, 1024, (long)M * 1024, BIG, 0, nullptr, nullptr, nullptr, M, 1024, 2048, 16);
    ffn2_reduce<<<M, 256, 0, stream>>>(fpart, b2 + (size_t)l * Dc, x);
  }

  anorm_kernel<<<M, 256, 0, stream>>>(x, final_gain, hbuf);
  gemm256_kernel<false, true, false, false><<<dim3(1000), 512, 0, stream>>>(
      hbuf, 1024, wlm_t, 1024,
      d_out, 32000, blm, nullptr, M, 32000, 1024, 8);
}